// Round 5
// baseline (525.023 us; speedup 1.0000x reference)
//
#include <hip/hip_runtime.h>
#include <math.h>

#define BB 16
#define LL 336
#define HH 192
#define CC 862
#define KK 8
#define FREQ 97
#define OUTD 1649      // 17*97
#define TTOT 528
#define WINL 240       // window covers t in [289, 528), 239 used + 1 pad
#define NBC (BB*CC)    // 13792
#define PI_F 3.14159265358979323846f

// ---------- kernel 1: per-(b,c) stats, classifier softmax p, corr, A ----------
__global__ __launch_bounds__(64) void k_stats(
    const float* __restrict__ x, const float* __restrict__ r_in,
    const float* __restrict__ temp, const float* __restrict__ cw,
    const float* __restrict__ bstate, const float* __restrict__ sbias,
    float* __restrict__ w_mu, float* __restrict__ w_std, float* __restrict__ w_istd,
    float* __restrict__ w_sgn, float* __restrict__ w_A)
{
    int bc = blockIdx.x*64 + threadIdx.x;
    if (bc >= NBC) return;
    int b = bc / CC, c = bc - b*CC;
    const float* xp = x + (size_t)b*LL*CC + c;
    float sum = 0.f, sq = 0.f;
    float lg[8];
#pragma unroll
    for (int s=0;s<8;++s) lg[s]=0.f;
    for (int l=0; l<LL; ++l){
        float v = xp[(size_t)l*CC];
        sum += v; sq += v*v;
#pragma unroll
        for (int s=0;s<8;++s) lg[s] = fmaf(v, cw[s*LL+l], lg[s]);
    }
    float mu   = sum * (1.f/LL);
    float var  = sq * (1.f/LL) - mu*mu;
    float stdv = sqrtf(var + 1e-8f);
    float istd = 1.f/stdv;
#pragma unroll
    for (int s=0;s<8;++s) lg[s] += sbias[s] + bstate[c*8+s];
    float m = lg[0];
#pragma unroll
    for (int s=1;s<8;++s) m = fmaxf(m, lg[s]);
    float p[8]; float den = 0.f;
#pragma unroll
    for (int s=0;s<8;++s){ p[s] = expf(lg[s]-m); den += p[s]; }
    float iden = 1.f/den;
#pragma unroll
    for (int s=0;s<8;++s) p[s] *= iden;

    float invT = 1.f / temp[0];
    float ek[8], sg[8];
    float dsum = expf(invT);     // the "ones" element
#pragma unroll
    for (int k=0;k<8;++k){
        float r = r_in[(size_t)bc*8 + k];
        sg[k] = (r > 0.f) ? 1.f : ((r < 0.f) ? -1.f : 0.f);
        ek[k] = expf(fabsf(r)*invT);
        dsum += ek[k];
    }
    float idsum = 1.f/dsum;

    w_mu[bc] = mu; w_std[bc] = stdv; w_istd[bc] = istd;
#pragma unroll
    for (int k=0;k<8;++k) w_sgn[(size_t)bc*8+k] = sg[k];
    float* Ar = w_A + (size_t)bc*80;
#pragma unroll
    for (int s=0;s<8;++s)
#pragma unroll
        for (int k=0;k<8;++k) Ar[s*8+k] = p[s]*(ek[k]*idsum);
#pragma unroll
    for (int s=0;s<8;++s) Ar[64+s] = p[s];
}

// ---------- kernel 2: build normalized window seq_all[t in 289..527] (transposed) ----------
__global__ __launch_bounds__(256) void k_win(
    const float* __restrict__ x, const float* __restrict__ y,
    const float* __restrict__ w_mu, const float* __restrict__ w_istd,
    float* __restrict__ win)
{
    __shared__ float buf[32][33];
    int b  = blockIdx.x;
    int t0 = blockIdx.y*32;
    int c0 = blockIdx.z*32;
    int tx = threadIdx.x, ty = threadIdx.y;   // 32 x 8
#pragma unroll
    for (int i=0;i<4;++i){
        int tl = ty + i*8;
        int t  = 289 + t0 + tl;
        int c  = c0 + tx;
        float v = 0.f;
        if (t < TTOT && c < CC){
            float raw = (t < LL) ? x[((size_t)b*LL + t)*CC + c]
                                 : y[((size_t)b*HH + (t-LL))*CC + c];
            int bc = b*CC + c;
            v = (raw - w_mu[bc]) * w_istd[bc];
        }
        buf[tl][tx] = v;
    }
    __syncthreads();
#pragma unroll
    for (int i=0;i<4;++i){
        int cl = ty + i*8;
        int c  = c0 + cl;
        int wl = t0 + tx;
        if (wl < 239 && c < CC)
            win[(size_t)(b*CC + c)*WINL + wl] = buf[tx][cl];
    }
}

// ---------- kernel 3: combined (w_c then irfft) real matrix PQ[582][192] + cst ----------
__global__ __launch_bounds__(640) void k_pq(
    const float* __restrict__ wr, const float* __restrict__ wi,
    const float* __restrict__ br, const float* __restrict__ bi,
    float* __restrict__ PQ, float* __restrict__ cst)
{
    int h = blockIdx.x;
    int tid = threadIdx.x;
    __shared__ float a_s[97], b_s[97], t_s[97];
    if (tid < 97){
        int o = tid;
        int mmod = (o*h) % 192;
        float th = (2.f*PI_F/192.f) * (float)mmod;
        float sn, cs; sincosf(th, &sn, &cs);
        float aa, bb;
        if (o == 0)      { aa = 1.f/192.f;                      bb = 0.f; }
        else if (o == 96){ aa = ((h&1)? -1.f:1.f)/192.f;        bb = 0.f; }
        else             { aa = 2.f*cs/192.f;                   bb = -2.f*sn/192.f; }
        a_s[o]=aa; b_s[o]=bb;
        t_s[o] = aa*br[o] + bb*bi[o];
    }
    __syncthreads();
    if (tid < 582){
        int j = tid;
        int isP = (j < 291);
        int jj = isP ? j : j-291;
        float acc = 0.f;
        for (int o=0;o<97;++o){
            float wrv = wr[o*291+jj], wiv = wi[o*291+jj];
            acc += isP ? (a_s[o]*wrv + b_s[o]*wiv)
                       : (b_s[o]*wrv - a_s[o]*wiv);
        }
        PQ[(size_t)j*HH + h] = acc;
    }
    if (tid == 0){
        float s = 0.f;
        for (int o=0;o<97;++o) s += t_s[o];
        cst[h] = s;
    }
}

// ---------- kernel 4: filt GEMM  (13792 x 80) x (80 x 1649), 8 rows/block ----------
__global__ __launch_bounds__(256) void k_filt(
    const float* __restrict__ A, const float* __restrict__ mhw,
    const float* __restrict__ mhb, float* __restrict__ filt)
{
    __shared__ float a_s[8][80];
    int tid = threadIdx.x;
    int bc0 = blockIdx.x*8;
    for (int i = tid; i < 640; i += 256)
        a_s[i/80][i%80] = A[(size_t)bc0*80 + i];
    __syncthreads();
    float acc[7][8];
#pragma unroll
    for (int i=0;i<7;++i)
#pragma unroll
        for (int r=0;r<8;++r) acc[i][r]=0.f;
    for (int j=0;j<80;++j){
        float ar[8];
#pragma unroll
        for (int r=0;r<8;++r) ar[r] = a_s[r][j];
        const float* wrow = (j < 64)
            ? (mhw + (size_t)(j>>3)*(KK*OUTD) + (size_t)(j&7)*OUTD)
            : (mhb + (size_t)(j-64)*OUTD);
#pragma unroll
        for (int i=0;i<7;++i){
            int o = tid + i*256;
            if (i < 6 || o < OUTD){
                float w = wrow[o];
#pragma unroll
                for (int r=0;r<8;++r) acc[i][r] = fmaf(ar[r], w, acc[i][r]);
            }
        }
    }
#pragma unroll
    for (int i=0;i<7;++i){
        int o = tid + i*256;
        if (i < 6 || o < OUTD){
#pragma unroll
            for (int r=0;r<8;++r) filt[(size_t)(bc0+r)*OUTD + o] = acc[i][r];
        }
    }
}

// ---------- kernel 5: gather + 9 real DFTs + filter apply -> mix_in ----------
__global__ __launch_bounds__(256) void k_dft(
    const float* __restrict__ win, const float* __restrict__ filt,
    const float* __restrict__ w_sgn, const int* __restrict__ leader,
    const int* __restrict__ shiftp, float* __restrict__ mixin)
{
    __shared__ __align__(16) float raw[9][192];
    __shared__ float sfl[9][97][2];
    __shared__ float fl[OUTD];
    __shared__ int   rbase[9];
    __shared__ float rsgn[9];
    int bc = blockIdx.x;
    int tid = threadIdx.x;
    int b = bc / CC, c = bc - b*CC;
    if (tid < 9){
        int k = tid;
        int src_c = c, sh = 0; float sg = 1.f;
        if (k < 8){
            src_c = leader[(size_t)bc*8 + k];
            sh    = shiftp[(size_t)bc*8 + k];
            sg    = w_sgn[(size_t)bc*8 + k];
        }
        rbase[k] = (b*CC + src_c)*WINL + 47 - sh;
        rsgn[k]  = sg;
    }
    __syncthreads();
    for (int i = tid; i < 9*192; i += 256){
        int r = i / 192, hh = i - r*192;
        raw[r][hh] = win[(size_t)rbase[r] + hh] * rsgn[r];
    }
    for (int i = tid; i < OUTD; i += 256) fl[i] = filt[(size_t)bc*OUTD + i];
    __syncthreads();
    // fold h / h+96 in place: raw[r][0..95]=even part, raw[r][96..191]=odd part
    float ev[4], ov[4];
#pragma unroll
    for (int q=0;q<4;++q){
        int i = tid + q*256;
        if (i < 864){
            int r = i/96, hh = i - r*96;
            float x0 = raw[r][hh], x1 = raw[r][hh+96];
            ev[q] = x0+x1; ov[q] = x0-x1;
        }
    }
    __syncthreads();
#pragma unroll
    for (int q=0;q<4;++q){
        int i = tid + q*256;
        if (i < 864){
            int r = i/96, hh = i - r*96;
            raw[r][hh] = ev[q]; raw[r][hh+96] = ov[q];
        }
    }
    __syncthreads();
    // DFT: s_f[k][f] = sum_{h<96} u_f[h] * w^{f h},  w = e^{-2pi i f/192}
    for (int pi = tid; pi < 873; pi += 256){
        int k = pi / 97, f = pi - k*97;
        const float4* row = (const float4*)&raw[k][(f & 1) ? 96 : 0];
        float sn, cs;
        sincosf(-(2.f*PI_F/192.f)*(float)f, &sn, &cs);
        float cx = 1.f, cy = 0.f, ax = 0.f, ay = 0.f;
#pragma unroll 6
        for (int hc = 0; hc < 24; ++hc){
            float4 xv = row[hc];
            float t;
            ax = fmaf(xv.x, cx, ax); ay = fmaf(xv.x, cy, ay);
            t = cx*cs - cy*sn; cy = fmaf(cx, sn, cy*cs); cx = t;
            ax = fmaf(xv.y, cx, ax); ay = fmaf(xv.y, cy, ay);
            t = cx*cs - cy*sn; cy = fmaf(cx, sn, cy*cs); cx = t;
            ax = fmaf(xv.z, cx, ax); ay = fmaf(xv.z, cy, ay);
            t = cx*cs - cy*sn; cy = fmaf(cx, sn, cy*cs); cx = t;
            ax = fmaf(xv.w, cx, ax); ay = fmaf(xv.w, cy, ay);
            t = cx*cs - cy*sn; cy = fmaf(cx, sn, cy*cs); cx = t;
        }
        sfl[k][f][0] = ax; sfl[k][f][1] = ay;
    }
    __syncthreads();
    if (tid < FREQ){
        int fr = tid;
        float yre = sfl[8][fr][0], yim = sfl[8][fr][1];
        float lre=0.f, lim=0.f, dre=0.f, dim_=0.f;
#pragma unroll
        for (int k=0;k<8;++k){
            float sre = sfl[k][fr][0], sim = sfl[k][fr][1];
            float f1 = fl[k*FREQ+fr], f2 = fl[(8+k)*FREQ+fr];
            lre = fmaf(sre, f1, lre);       lim  = fmaf(sim, f1, lim);
            dre = fmaf(sre-yre, f2, dre);   dim_ = fmaf(sim-yim, f2, dim_);
        }
        float f3 = fl[16*FREQ+fr];
        float* mrow = mixin + (size_t)bc*582;
        mrow[fr]           = lre;
        mrow[97 + fr]      = dre;
        mrow[194 + fr]     = yre*f3;
        mrow[291 + fr]     = lim;
        mrow[291+97 + fr]  = dim_;
        mrow[291+194 + fr] = yim*f3;
    }
}

// ---------- kernel 6: y_add GEMM (13792 x 582)x(582 x 192) + denorm + transposed store ----------
__global__ __launch_bounds__(192) void k_mix(
    const float* __restrict__ mixin, const float* __restrict__ PQ,
    const float* __restrict__ cst, const float* __restrict__ win,
    const float* __restrict__ w_mu, const float* __restrict__ w_std,
    float* __restrict__ out)
{
    __shared__ __align__(16) float At[582][20];
    int tid = threadIdx.x;
    int bc0 = blockIdx.x*16;
    for (int i = tid; i < 16*582; i += 192){
        int r = i / 582, j = i - r*582;
        At[j][r] = mixin[(size_t)(bc0+r)*582 + j];
    }
    __syncthreads();
    int rg = tid / 48, cg = tid - (tid/48)*48;   // rows rg*4.., cols cg*4..
    float acc[4][4];
#pragma unroll
    for (int r=0;r<4;++r)
#pragma unroll
        for (int hh=0;hh<4;++hh) acc[r][hh]=0.f;
    const float* pqbase = PQ + cg*4;
    for (int j=0;j<582;++j){
        float4 av = *(const float4*)&At[j][rg*4];
        float4 wv = *(const float4*)(pqbase + (size_t)j*HH);
        acc[0][0] = fmaf(av.x, wv.x, acc[0][0]);
        acc[0][1] = fmaf(av.x, wv.y, acc[0][1]);
        acc[0][2] = fmaf(av.x, wv.z, acc[0][2]);
        acc[0][3] = fmaf(av.x, wv.w, acc[0][3]);
        acc[1][0] = fmaf(av.y, wv.x, acc[1][0]);
        acc[1][1] = fmaf(av.y, wv.y, acc[1][1]);
        acc[1][2] = fmaf(av.y, wv.z, acc[1][2]);
        acc[1][3] = fmaf(av.y, wv.w, acc[1][3]);
        acc[2][0] = fmaf(av.z, wv.x, acc[2][0]);
        acc[2][1] = fmaf(av.z, wv.y, acc[2][1]);
        acc[2][2] = fmaf(av.z, wv.z, acc[2][2]);
        acc[2][3] = fmaf(av.z, wv.w, acc[2][3]);
        acc[3][0] = fmaf(av.w, wv.x, acc[3][0]);
        acc[3][1] = fmaf(av.w, wv.y, acc[3][1]);
        acc[3][2] = fmaf(av.w, wv.z, acc[3][2]);
        acc[3][3] = fmaf(av.w, wv.w, acc[3][3]);
    }
    float cst4[4];
#pragma unroll
    for (int hh=0;hh<4;++hh) cst4[hh] = cst[cg*4+hh];
#pragma unroll
    for (int rr=0; rr<4; ++rr){
        int bc = bc0 + rg*4 + rr;
        int b = bc / CC, c = bc - b*CC;
        float muv = w_mu[bc], stv = w_std[bc];
#pragma unroll
        for (int hh=0; hh<4; ++hh){
            int h = cg*4 + hh;
            float yn = win[(size_t)bc*WINL + 47 + h];
            float v = (acc[rr][hh] + cst4[hh] + yn)*stv + muv;
            out[((size_t)b*HH + h)*CC + c] = v;
        }
    }
}

extern "C" void kernel_launch(void* const* d_in, const int* in_sizes, int n_in,
                              void* d_out, int out_size, void* d_ws, size_t ws_size,
                              hipStream_t stream) {
    const float* x      = (const float*)d_in[0];
    const float* y      = (const float*)d_in[1];
    const float* r_in   = (const float*)d_in[2];
    const float* temp   = (const float*)d_in[3];
    const float* cw     = (const float*)d_in[4];
    const float* bstate = (const float*)d_in[5];
    const float* sbias  = (const float*)d_in[6];
    const float* mhw    = (const float*)d_in[7];
    const float* mhb    = (const float*)d_in[8];
    const float* wr     = (const float*)d_in[9];
    const float* wi     = (const float*)d_in[10];
    const float* br     = (const float*)d_in[11];
    const float* bi     = (const float*)d_in[12];
    const int*   leader = (const int*)d_in[13];
    const int*   shiftp = (const int*)d_in[14];
    float* ws  = (float*)d_ws;
    float* out = (float*)d_out;

    size_t o_win  = 0;
    size_t o_mu   = o_win  + (size_t)NBC*WINL;
    size_t o_std  = o_mu   + NBC;
    size_t o_istd = o_std  + NBC;
    size_t o_sgn  = o_istd + NBC;
    size_t o_A    = o_sgn  + (size_t)NBC*8;
    size_t o_filt = o_A    + (size_t)NBC*80;
    size_t o_mix  = o_filt + (size_t)NBC*OUTD;
    size_t o_PQ   = o_mix  + (size_t)NBC*582;
    size_t o_cst  = o_PQ   + (size_t)582*HH;

    k_stats<<<dim3((NBC+63)/64), dim3(64), 0, stream>>>(
        x, r_in, temp, cw, bstate, sbias,
        ws+o_mu, ws+o_std, ws+o_istd, ws+o_sgn, ws+o_A);

    k_win<<<dim3(BB, 8, 27), dim3(32, 8), 0, stream>>>(
        x, y, ws+o_mu, ws+o_istd, ws+o_win);

    k_pq<<<dim3(HH), dim3(640), 0, stream>>>(
        wr, wi, br, bi, ws+o_PQ, ws+o_cst);

    k_filt<<<dim3(NBC/8), dim3(256), 0, stream>>>(
        ws+o_A, mhw, mhb, ws+o_filt);

    k_dft<<<dim3(NBC), dim3(256), 0, stream>>>(
        ws+o_win, ws+o_filt, ws+o_sgn, leader, shiftp, ws+o_mix);

    k_mix<<<dim3(NBC/16), dim3(192), 0, stream>>>(
        ws+o_mix, ws+o_PQ, ws+o_cst, ws+o_win, ws+o_mu, ws+o_std, out);
}

// Round 10
// 435.132 us; speedup vs baseline: 1.2066x; 1.2066x over previous
//
#include <hip/hip_runtime.h>
#include <math.h>

#define BB 16
#define LL 336
#define HH 192
#define CC 862
#define KK 8
#define FREQ 97
#define OUTD 1649      // 17*97
#define TTOT 528
#define WINL 240       // window covers t in [289, 528), 239 used + 1 pad
#define NBC (BB*CC)    // 13792
#define PI_F 3.14159265358979323846f

typedef __attribute__((ext_vector_type(8))) short bf16x8;
typedef __attribute__((ext_vector_type(4))) float f32x4;

static __device__ __forceinline__ ushort f2bf(float f){
    unsigned u = __float_as_uint(f);
    unsigned r = (u + 0x7FFFu + ((u >> 16) & 1u)) >> 16;   // RNE
    return (ushort)r;
}

// ---------- kernel 1: per-(b,c) stats, classifier softmax p, corr, A ----------
__global__ __launch_bounds__(64) void k_stats(
    const float* __restrict__ x, const float* __restrict__ r_in,
    const float* __restrict__ temp, const float* __restrict__ cw,
    const float* __restrict__ bstate, const float* __restrict__ sbias,
    float* __restrict__ w_mu, float* __restrict__ w_std, float* __restrict__ w_istd,
    float* __restrict__ w_sgn, float* __restrict__ w_A)
{
    int bc = blockIdx.x*64 + threadIdx.x;
    if (bc >= NBC) return;
    int b = bc / CC, c = bc - b*CC;
    const float* xp = x + (size_t)b*LL*CC + c;
    float sum = 0.f, sq = 0.f;
    float lg[8];
#pragma unroll
    for (int s=0;s<8;++s) lg[s]=0.f;
    for (int l=0; l<LL; ++l){
        float v = xp[(size_t)l*CC];
        sum += v; sq += v*v;
#pragma unroll
        for (int s=0;s<8;++s) lg[s] = fmaf(v, cw[s*LL+l], lg[s]);
    }
    float mu   = sum * (1.f/LL);
    float var  = sq * (1.f/LL) - mu*mu;
    float stdv = sqrtf(var + 1e-8f);
    float istd = 1.f/stdv;
#pragma unroll
    for (int s=0;s<8;++s) lg[s] += sbias[s] + bstate[c*8+s];
    float m = lg[0];
#pragma unroll
    for (int s=1;s<8;++s) m = fmaxf(m, lg[s]);
    float p[8]; float den = 0.f;
#pragma unroll
    for (int s=0;s<8;++s){ p[s] = expf(lg[s]-m); den += p[s]; }
    float iden = 1.f/den;
#pragma unroll
    for (int s=0;s<8;++s) p[s] *= iden;

    float invT = 1.f / temp[0];
    float ek[8], sg[8];
    float dsum = expf(invT);     // the "ones" element
#pragma unroll
    for (int k=0;k<8;++k){
        float r = r_in[(size_t)bc*8 + k];
        sg[k] = (r > 0.f) ? 1.f : ((r < 0.f) ? -1.f : 0.f);
        ek[k] = expf(fabsf(r)*invT);
        dsum += ek[k];
    }
    float idsum = 1.f/dsum;

    w_mu[bc] = mu; w_std[bc] = stdv; w_istd[bc] = istd;
#pragma unroll
    for (int k=0;k<8;++k) w_sgn[(size_t)bc*8+k] = sg[k];
    float* Ar = w_A + (size_t)bc*80;
#pragma unroll
    for (int s=0;s<8;++s)
#pragma unroll
        for (int k=0;k<8;++k) Ar[s*8+k] = p[s]*(ek[k]*idsum);
#pragma unroll
    for (int s=0;s<8;++s) Ar[64+s] = p[s];
}

// ---------- kernel 2: build normalized window seq_all[t in 289..527] (transposed) ----------
__global__ __launch_bounds__(256) void k_win(
    const float* __restrict__ x, const float* __restrict__ y,
    const float* __restrict__ w_mu, const float* __restrict__ w_istd,
    float* __restrict__ win)
{
    __shared__ float buf[32][33];
    int b  = blockIdx.x;
    int t0 = blockIdx.y*32;
    int c0 = blockIdx.z*32;
    int tx = threadIdx.x, ty = threadIdx.y;   // 32 x 8
#pragma unroll
    for (int i=0;i<4;++i){
        int tl = ty + i*8;
        int t  = 289 + t0 + tl;
        int c  = c0 + tx;
        float v = 0.f;
        if (t < TTOT && c < CC){
            float raw = (t < LL) ? x[((size_t)b*LL + t)*CC + c]
                                 : y[((size_t)b*HH + (t-LL))*CC + c];
            int bc = b*CC + c;
            v = (raw - w_mu[bc]) * w_istd[bc];
        }
        buf[tl][tx] = v;
    }
    __syncthreads();
#pragma unroll
    for (int i=0;i<4;++i){
        int cl = ty + i*8;
        int c  = c0 + cl;
        int wl = t0 + tx;
        if (wl < 239 && c < CC)
            win[(size_t)(b*CC + c)*WINL + wl] = buf[tx][cl];
    }
}

// ---------- kernel 3: combined (w_c then irfft) real matrix PQ[582][192] + cst ----------
__global__ __launch_bounds__(640) void k_pq(
    const float* __restrict__ wr, const float* __restrict__ wi,
    const float* __restrict__ br, const float* __restrict__ bi,
    float* __restrict__ PQ, float* __restrict__ cst)
{
    int h = blockIdx.x;
    int tid = threadIdx.x;
    __shared__ float a_s[97], b_s[97], t_s[97];
    if (tid < 97){
        int o = tid;
        int mmod = (o*h) % 192;
        float th = (2.f*PI_F/192.f) * (float)mmod;
        float sn, cs; sincosf(th, &sn, &cs);
        float aa, bb;
        if (o == 0)      { aa = 1.f/192.f;                      bb = 0.f; }
        else if (o == 96){ aa = ((h&1)? -1.f:1.f)/192.f;        bb = 0.f; }
        else             { aa = 2.f*cs/192.f;                   bb = -2.f*sn/192.f; }
        a_s[o]=aa; b_s[o]=bb;
        t_s[o] = aa*br[o] + bb*bi[o];
    }
    __syncthreads();
    if (tid < 582){
        int j = tid;
        int isP = (j < 291);
        int jj = isP ? j : j-291;
        float acc = 0.f;
        for (int o=0;o<97;++o){
            float wrv = wr[o*291+jj], wiv = wi[o*291+jj];
            acc += isP ? (a_s[o]*wrv + b_s[o]*wiv)
                       : (b_s[o]*wrv - a_s[o]*wiv);
        }
        PQ[(size_t)j*HH + h] = acc;
    }
    if (tid == 0){
        float s = 0.f;
        for (int o=0;o<97;++o) s += t_s[o];
        cst[h] = s;
    }
}

// ---------- kernel 3b: DFT matrix in MFMA B-fragment layout (bf16) ----------
// 13 N-tiles: t=0..6 even bins (ue side, angle 2*pi*g*k/96, n=2g+reim, n<98),
//             t=7..12 odd bins (uo side, angle 2*pi*f*k/192, f=n|1)
// layout: bfrag[((t*3+kk)*64 + lane)*8 + j] = B[k = kk*32+(lane>>4)*8+j][n = t*16+(lane&15)]
__global__ __launch_bounds__(256) void k_bfrag(ushort* __restrict__ bfrag)
{
    int idx = blockIdx.x*256 + threadIdx.x;
    const int total = 13*3*64*8;   // 19968
    if (idx >= total) return;
    int j  = idx & 7;
    int l  = (idx >> 3) & 63;
    int tk = idx >> 9;             // tile*3 + kk
    int t  = tk / 3, kk = tk - t*3;
    int k  = kk*32 + ((l>>4)<<3) + j;
    int nl = l & 15;
    float v = 0.f;
    if (t < 7){
        int n = t*16 + nl;
        if (n < 98){
            int g  = n >> 1;
            int mm = (g*k) % 96;
            float th = (2.f*PI_F/96.f)*(float)mm;
            float sn, cs; sincosf(th, &sn, &cs);
            v = (n & 1) ? -sn : cs;
        }
    } else {
        int n = (t-7)*16 + nl;
        int f = n | 1;
        int mm = (f*k) % 192;
        float th = (2.f*PI_F/192.f)*(float)mm;
        float sn, cs; sincosf(th, &sn, &cs);
        v = (n & 1) ? -sn : cs;
    }
    bfrag[idx] = f2bf(v);
}

// ---------- kernel 4: filt GEMM  (13792 x 80) x (80 x 1649), 8 rows/block ----------
__global__ __launch_bounds__(256) void k_filt(
    const float* __restrict__ A, const float* __restrict__ mhw,
    const float* __restrict__ mhb, float* __restrict__ filt)
{
    __shared__ float a_s[8][80];
    int tid = threadIdx.x;
    int bc0 = blockIdx.x*8;
    for (int i = tid; i < 640; i += 256)
        a_s[i/80][i%80] = A[(size_t)bc0*80 + i];
    __syncthreads();
    float acc[7][8];
#pragma unroll
    for (int i=0;i<7;++i)
#pragma unroll
        for (int r=0;r<8;++r) acc[i][r]=0.f;
    for (int j=0;j<80;++j){
        float ar[8];
#pragma unroll
        for (int r=0;r<8;++r) ar[r] = a_s[r][j];
        const float* wrow = (j < 64)
            ? (mhw + (size_t)(j>>3)*(KK*OUTD) + (size_t)(j&7)*OUTD)
            : (mhb + (size_t)(j-64)*OUTD);
#pragma unroll
        for (int i=0;i<7;++i){
            int o = tid + i*256;
            if (i < 6 || o < OUTD){
                float w = wrow[o];
#pragma unroll
                for (int r=0;r<8;++r) acc[i][r] = fmaf(ar[r], w, acc[i][r]);
            }
        }
    }
#pragma unroll
    for (int i=0;i<7;++i){
        int o = tid + i*256;
        if (i < 6 || o < OUTD){
#pragma unroll
            for (int r=0;r<8;++r) filt[(size_t)(bc0+r)*OUTD + o] = acc[i][r];
        }
    }
}

// ---------- kernel 5: gather + MFMA DFT (9 rows, fold even/odd) + filter apply ----------
__global__ __launch_bounds__(256) void k_dft(
    const float* __restrict__ win, const float* __restrict__ filt,
    const float* __restrict__ w_sgn, const int* __restrict__ leader,
    const int* __restrict__ shiftp, const ushort* __restrict__ bfrag,
    float* __restrict__ mixin)
{
    __shared__ __align__(16) float raw[9][192];
    __shared__ __align__(16) ushort Ae[16*104];   // row stride 104 bf16 = 208B (conflict-free)
    __shared__ __align__(16) ushort Ao[16*104];
    __shared__ float sfl[9][97][2];
    __shared__ float fl[OUTD];
    __shared__ int   rbase[9];
    __shared__ float rsgn[9];
    int bc = blockIdx.x;
    int tid = threadIdx.x;
    int b = bc / CC, c = bc - b*CC;
    if (tid < 9){
        int k = tid;
        int src_c = c, sh = 0; float sg = 1.f;
        if (k < 8){
            src_c = leader[(size_t)bc*8 + k];
            sh    = shiftp[(size_t)bc*8 + k];
            sg    = w_sgn[(size_t)bc*8 + k];
        }
        rbase[k] = (b*CC + src_c)*WINL + 47 - sh;
        rsgn[k]  = sg;
    }
    __syncthreads();
    for (int i = tid; i < 9*192; i += 256){
        int r = i / 192, hh = i - r*192;
        raw[r][hh] = win[(size_t)rbase[r] + hh] * rsgn[r];
    }
    for (int i = tid; i < OUTD; i += 256) fl[i] = filt[(size_t)bc*OUTD + i];
    __syncthreads();
    // fold h/h+96 and pack to bf16 MFMA A-operand layout (rows 9..15 unused garbage, never read)
    for (int i = tid; i < 864; i += 256){
        int r = i/96, hh = i - r*96;
        float x0 = raw[r][hh], x1 = raw[r][hh+96];
        Ae[r*104+hh] = f2bf(x0 + x1);
        Ao[r*104+hh] = f2bf(x0 - x1);
    }
    __syncthreads();
    // 13 N-tiles x 3 K-steps of v_mfma_f32_16x16x32_bf16
    int wid = tid >> 6, lane = tid & 63;
    int lrow = lane & 15;               // A row / B col / D col
    int lk8  = (lane >> 4) << 3;        // k offset within K=32
    for (int t = wid; t < 13; t += 4){
        const ushort* Ab = (t < 7) ? Ae : Ao;
        const ushort* bb = bfrag + (size_t)(t*3)*512;
        f32x4 acc = {0.f, 0.f, 0.f, 0.f};
#pragma unroll
        for (int kk = 0; kk < 3; ++kk){
            bf16x8 a = *(const bf16x8*)&Ab[lrow*104 + kk*32 + lk8];
            bf16x8 bfr = *(const bf16x8*)&bb[kk*512 + lane*8];
            acc = __builtin_amdgcn_mfma_f32_16x16x32_bf16(a, bfr, acc, 0, 0, 0);
        }
        int row0 = (lane >> 4) * 4;     // D: row=(lane>>4)*4+reg, col=lane&15  [m89]
#pragma unroll
        for (int r = 0; r < 4; ++r){
            int row = row0 + r;
            if (row <= 8){
                if (t < 7){
                    int n = t*16 + lrow;
                    if (n < 98) sfl[row][n - (n&1)][n&1] = acc[r];
                } else {
                    int n = (t-7)*16 + lrow;
                    sfl[row][n | 1][n&1] = acc[r];
                }
            }
        }
    }
    __syncthreads();
    if (tid < FREQ){
        int fr = tid;
        float yre = sfl[8][fr][0], yim = sfl[8][fr][1];
        float lre=0.f, lim=0.f, dre=0.f, dim_=0.f;
#pragma unroll
        for (int k=0;k<8;++k){
            float sre = sfl[k][fr][0], sim = sfl[k][fr][1];
            float f1 = fl[k*FREQ+fr], f2 = fl[(8+k)*FREQ+fr];
            lre = fmaf(sre, f1, lre);       lim  = fmaf(sim, f1, lim);
            dre = fmaf(sre-yre, f2, dre);   dim_ = fmaf(sim-yim, f2, dim_);
        }
        float f3 = fl[16*FREQ+fr];
        float* mrow = mixin + (size_t)bc*582;
        mrow[fr]           = lre;
        mrow[97 + fr]      = dre;
        mrow[194 + fr]     = yre*f3;
        mrow[291 + fr]     = lim;
        mrow[291+97 + fr]  = dim_;
        mrow[291+194 + fr] = yim*f3;
    }
}

// ---------- kernel 6: y_add GEMM (13792 x 582)x(582 x 192) + denorm + transposed store ----------
__global__ __launch_bounds__(192) void k_mix(
    const float* __restrict__ mixin, const float* __restrict__ PQ,
    const float* __restrict__ cst, const float* __restrict__ win,
    const float* __restrict__ w_mu, const float* __restrict__ w_std,
    float* __restrict__ out)
{
    __shared__ __align__(16) float At[582][20];
    int tid = threadIdx.x;
    int bc0 = blockIdx.x*16;
    for (int i = tid; i < 16*582; i += 192){
        int r = i / 582, j = i - r*582;
        At[j][r] = mixin[(size_t)(bc0+r)*582 + j];
    }
    __syncthreads();
    int rg = tid / 48, cg = tid - (tid/48)*48;   // rows rg*4.., cols cg*4..
    float acc[4][4];
#pragma unroll
    for (int r=0;r<4;++r)
#pragma unroll
        for (int hh=0;hh<4;++hh) acc[r][hh]=0.f;
    const float* pqbase = PQ + cg*4;
    for (int j=0;j<582;++j){
        float4 av = *(const float4*)&At[j][rg*4];
        float4 wv = *(const float4*)(pqbase + (size_t)j*HH);
        acc[0][0] = fmaf(av.x, wv.x, acc[0][0]);
        acc[0][1] = fmaf(av.x, wv.y, acc[0][1]);
        acc[0][2] = fmaf(av.x, wv.z, acc[0][2]);
        acc[0][3] = fmaf(av.x, wv.w, acc[0][3]);
        acc[1][0] = fmaf(av.y, wv.x, acc[1][0]);
        acc[1][1] = fmaf(av.y, wv.y, acc[1][1]);
        acc[1][2] = fmaf(av.y, wv.z, acc[1][2]);
        acc[1][3] = fmaf(av.y, wv.w, acc[1][3]);
        acc[2][0] = fmaf(av.z, wv.x, acc[2][0]);
        acc[2][1] = fmaf(av.z, wv.y, acc[2][1]);
        acc[2][2] = fmaf(av.z, wv.z, acc[2][2]);
        acc[2][3] = fmaf(av.z, wv.w, acc[2][3]);
        acc[3][0] = fmaf(av.w, wv.x, acc[3][0]);
        acc[3][1] = fmaf(av.w, wv.y, acc[3][1]);
        acc[3][2] = fmaf(av.w, wv.z, acc[3][2]);
        acc[3][3] = fmaf(av.w, wv.w, acc[3][3]);
    }
    float cst4[4];
#pragma unroll
    for (int hh=0;hh<4;++hh) cst4[hh] = cst[cg*4+hh];
#pragma unroll
    for (int rr=0; rr<4; ++rr){
        int bc = bc0 + rg*4 + rr;
        int b = bc / CC, c = bc - b*CC;
        float muv = w_mu[bc], stv = w_std[bc];
#pragma unroll
        for (int hh=0; hh<4; ++hh){
            int h = cg*4 + hh;
            float yn = win[(size_t)bc*WINL + 47 + h];
            float v = (acc[rr][hh] + cst4[hh] + yn)*stv + muv;
            out[((size_t)b*HH + h)*CC + c] = v;
        }
    }
}

extern "C" void kernel_launch(void* const* d_in, const int* in_sizes, int n_in,
                              void* d_out, int out_size, void* d_ws, size_t ws_size,
                              hipStream_t stream) {
    const float* x      = (const float*)d_in[0];
    const float* y      = (const float*)d_in[1];
    const float* r_in   = (const float*)d_in[2];
    const float* temp   = (const float*)d_in[3];
    const float* cw     = (const float*)d_in[4];
    const float* bstate = (const float*)d_in[5];
    const float* sbias  = (const float*)d_in[6];
    const float* mhw    = (const float*)d_in[7];
    const float* mhb    = (const float*)d_in[8];
    const float* wr     = (const float*)d_in[9];
    const float* wi     = (const float*)d_in[10];
    const float* br     = (const float*)d_in[11];
    const float* bi     = (const float*)d_in[12];
    const int*   leader = (const int*)d_in[13];
    const int*   shiftp = (const int*)d_in[14];
    float* ws  = (float*)d_ws;
    float* out = (float*)d_out;

    size_t o_win  = 0;
    size_t o_mu   = o_win  + (size_t)NBC*WINL;
    size_t o_std  = o_mu   + NBC;
    size_t o_istd = o_std  + NBC;
    size_t o_sgn  = o_istd + NBC;
    size_t o_A    = o_sgn  + (size_t)NBC*8;
    size_t o_filt = o_A    + (size_t)NBC*80;
    size_t o_mix  = o_filt + (size_t)NBC*OUTD;
    size_t o_PQ   = o_mix  + (size_t)NBC*582;
    size_t o_cst  = o_PQ   + (size_t)582*HH;
    size_t o_bfr  = o_cst  + HH;             // 19968 ushorts (9984 floats), 16B aligned
    ushort* bfrag = (ushort*)(ws + o_bfr);

    k_stats<<<dim3((NBC+63)/64), dim3(64), 0, stream>>>(
        x, r_in, temp, cw, bstate, sbias,
        ws+o_mu, ws+o_std, ws+o_istd, ws+o_sgn, ws+o_A);

    k_win<<<dim3(BB, 8, 27), dim3(32, 8), 0, stream>>>(
        x, y, ws+o_mu, ws+o_istd, ws+o_win);

    k_pq<<<dim3(HH), dim3(640), 0, stream>>>(
        wr, wi, br, bi, ws+o_PQ, ws+o_cst);

    k_bfrag<<<dim3(78), dim3(256), 0, stream>>>(bfrag);

    k_filt<<<dim3(NBC/8), dim3(256), 0, stream>>>(
        ws+o_A, mhw, mhb, ws+o_filt);

    k_dft<<<dim3(NBC), dim3(256), 0, stream>>>(
        ws+o_win, ws+o_filt, ws+o_sgn, leader, shiftp, bfrag, ws+o_mix);

    k_mix<<<dim3(NBC/16), dim3(192), 0, stream>>>(
        ws+o_mix, ws+o_PQ, ws+o_cst, ws+o_win, ws+o_mu, ws+o_std, out);
}

// Round 11
// 309.886 us; speedup vs baseline: 1.6942x; 1.4042x over previous
//
#include <hip/hip_runtime.h>
#include <math.h>

#define BB 16
#define LL 336
#define HH 192
#define CC 862
#define KK 8
#define FREQ 97
#define OUTD 1649      // 17*97
#define TTOT 528
#define WINL 240       // window covers t in [289, 528), 239 used + 1 pad
#define NBC (BB*CC)    // 13792
#define PI_F 3.14159265358979323846f
#define WT 104         // N-tiles in wfrag (1664 = 104*16)
#define MIX_KS 19      // K-steps in pqfrag (608 = 19*32)

typedef __attribute__((ext_vector_type(8))) short bf16x8;
typedef __attribute__((ext_vector_type(4))) float f32x4;

static __device__ __forceinline__ ushort f2bf(float f){
    unsigned u = __float_as_uint(f);
    unsigned r = (u + 0x7FFFu + ((u >> 16) & 1u)) >> 16;   // RNE
    return (ushort)r;
}
static __device__ __forceinline__ float bf2f(ushort u){
    return __uint_as_float(((unsigned)u) << 16);
}

// ---------- kernel 1: per-(b,c) stats, classifier softmax p, corr, A ----------
__global__ __launch_bounds__(64) void k_stats(
    const float* __restrict__ x, const float* __restrict__ r_in,
    const float* __restrict__ temp, const float* __restrict__ cw,
    const float* __restrict__ bstate, const float* __restrict__ sbias,
    float* __restrict__ w_mu, float* __restrict__ w_std, float* __restrict__ w_istd,
    float* __restrict__ w_sgn, float* __restrict__ w_A)
{
    int bc = blockIdx.x*64 + threadIdx.x;
    if (bc >= NBC) return;
    int b = bc / CC, c = bc - b*CC;
    const float* xp = x + (size_t)b*LL*CC + c;
    float sum = 0.f, sq = 0.f;
    float lg[8];
#pragma unroll
    for (int s=0;s<8;++s) lg[s]=0.f;
    for (int l=0; l<LL; ++l){
        float v = xp[(size_t)l*CC];
        sum += v; sq += v*v;
#pragma unroll
        for (int s=0;s<8;++s) lg[s] = fmaf(v, cw[s*LL+l], lg[s]);
    }
    float mu   = sum * (1.f/LL);
    float var  = sq * (1.f/LL) - mu*mu;
    float stdv = sqrtf(var + 1e-8f);
    float istd = 1.f/stdv;
#pragma unroll
    for (int s=0;s<8;++s) lg[s] += sbias[s] + bstate[c*8+s];
    float m = lg[0];
#pragma unroll
    for (int s=1;s<8;++s) m = fmaxf(m, lg[s]);
    float p[8]; float den = 0.f;
#pragma unroll
    for (int s=0;s<8;++s){ p[s] = expf(lg[s]-m); den += p[s]; }
    float iden = 1.f/den;
#pragma unroll
    for (int s=0;s<8;++s) p[s] *= iden;

    float invT = 1.f / temp[0];
    float ek[8], sg[8];
    float dsum = expf(invT);     // the "ones" element
#pragma unroll
    for (int k=0;k<8;++k){
        float r = r_in[(size_t)bc*8 + k];
        sg[k] = (r > 0.f) ? 1.f : ((r < 0.f) ? -1.f : 0.f);
        ek[k] = expf(fabsf(r)*invT);
        dsum += ek[k];
    }
    float idsum = 1.f/dsum;

    w_mu[bc] = mu; w_std[bc] = stdv; w_istd[bc] = istd;
#pragma unroll
    for (int k=0;k<8;++k) w_sgn[(size_t)bc*8+k] = sg[k];
    float* Ar = w_A + (size_t)bc*80;
#pragma unroll
    for (int s=0;s<8;++s)
#pragma unroll
        for (int k=0;k<8;++k) Ar[s*8+k] = p[s]*(ek[k]*idsum);
#pragma unroll
    for (int s=0;s<8;++s) Ar[64+s] = p[s];
}

// ---------- kernel 2: build normalized window seq_all[t in 289..527] (transposed) ----------
__global__ __launch_bounds__(256) void k_win(
    const float* __restrict__ x, const float* __restrict__ y,
    const float* __restrict__ w_mu, const float* __restrict__ w_istd,
    float* __restrict__ win)
{
    __shared__ float buf[32][33];
    int b  = blockIdx.x;
    int t0 = blockIdx.y*32;
    int c0 = blockIdx.z*32;
    int tx = threadIdx.x, ty = threadIdx.y;   // 32 x 8
#pragma unroll
    for (int i=0;i<4;++i){
        int tl = ty + i*8;
        int t  = 289 + t0 + tl;
        int c  = c0 + tx;
        float v = 0.f;
        if (t < TTOT && c < CC){
            float raw = (t < LL) ? x[((size_t)b*LL + t)*CC + c]
                                 : y[((size_t)b*HH + (t-LL))*CC + c];
            int bc = b*CC + c;
            v = (raw - w_mu[bc]) * w_istd[bc];
        }
        buf[tl][tx] = v;
    }
    __syncthreads();
#pragma unroll
    for (int i=0;i<4;++i){
        int cl = ty + i*8;
        int c  = c0 + cl;
        int wl = t0 + tx;
        if (wl < 239 && c < CC)
            win[(size_t)(b*CC + c)*WINL + wl] = buf[tx][cl];
    }
}

// ---------- kernel 3: combined (w_c then irfft) real matrix PQ[582][192] + cst ----------
__global__ __launch_bounds__(640) void k_pq(
    const float* __restrict__ wr, const float* __restrict__ wi,
    const float* __restrict__ br, const float* __restrict__ bi,
    float* __restrict__ PQ, float* __restrict__ cst)
{
    int h = blockIdx.x;
    int tid = threadIdx.x;
    __shared__ float a_s[97], b_s[97], t_s[97];
    if (tid < 97){
        int o = tid;
        int mmod = (o*h) % 192;
        float th = (2.f*PI_F/192.f) * (float)mmod;
        float sn, cs; sincosf(th, &sn, &cs);
        float aa, bb;
        if (o == 0)      { aa = 1.f/192.f;                      bb = 0.f; }
        else if (o == 96){ aa = ((h&1)? -1.f:1.f)/192.f;        bb = 0.f; }
        else             { aa = 2.f*cs/192.f;                   bb = -2.f*sn/192.f; }
        a_s[o]=aa; b_s[o]=bb;
        t_s[o] = aa*br[o] + bb*bi[o];
    }
    __syncthreads();
    if (tid < 582){
        int j = tid;
        int isP = (j < 291);
        int jj = isP ? j : j-291;
        float acc = 0.f;
        for (int o=0;o<97;++o){
            float wrv = wr[o*291+jj], wiv = wi[o*291+jj];
            acc += isP ? (a_s[o]*wrv + b_s[o]*wiv)
                       : (b_s[o]*wrv - a_s[o]*wiv);
        }
        PQ[(size_t)j*HH + h] = acc;
    }
    if (tid == 0){
        float s = 0.f;
        for (int o=0;o<97;++o) s += t_s[o];
        cst[h] = s;
    }
}

// ---------- kernel 3b: DFT matrix in MFMA B-fragment layout (bf16) ----------
__global__ __launch_bounds__(256) void k_bfrag(ushort* __restrict__ bfrag)
{
    int idx = blockIdx.x*256 + threadIdx.x;
    const int total = 13*3*64*8;   // 19968
    if (idx >= total) return;
    int j  = idx & 7;
    int l  = (idx >> 3) & 63;
    int tk = idx >> 9;             // tile*3 + kk
    int t  = tk / 3, kk = tk - t*3;
    int k  = kk*32 + ((l>>4)<<3) + j;
    int nl = l & 15;
    float v = 0.f;
    if (t < 7){
        int n = t*16 + nl;
        if (n < 98){
            int g  = n >> 1;
            int mm = (g*k) % 96;
            float th = (2.f*PI_F/96.f)*(float)mm;
            float sn, cs; sincosf(th, &sn, &cs);
            v = (n & 1) ? -sn : cs;
        }
    } else {
        int n = (t-7)*16 + nl;
        int f = n | 1;
        int mm = (f*k) % 192;
        float th = (2.f*PI_F/192.f)*(float)mm;
        float sn, cs; sincosf(th, &sn, &cs);
        v = (n & 1) ? -sn : cs;
    }
    bfrag[idx] = f2bf(v);
}

// ---------- kernel 3c: mix_head weights -> MFMA B-fragment layout (bf16) ----------
// W[j=s*8+k or 64+s][o]; K=80 pad 96, N=1649 pad 1664 (104 tiles)
__global__ __launch_bounds__(256) void k_wpack(
    const float* __restrict__ mhw, const float* __restrict__ mhb,
    ushort* __restrict__ wfrag)
{
    int idx = blockIdx.x*256 + threadIdx.x;
    const int total = WT*3*64*8;   // 159744
    if (idx >= total) return;
    int j  = idx & 7;
    int l  = (idx >> 3) & 63;
    int tk = idx >> 9;             // tile*3 + kk
    int t  = tk / 3, kk = tk - t*3;
    int k  = kk*32 + ((l>>4)<<3) + j;   // 0..95
    int n  = t*16 + (l & 15);           // 0..1663
    float v = 0.f;
    if (n < OUTD && k < 80){
        v = (k < 64) ? mhw[(size_t)(k>>3)*(8*OUTD) + (size_t)(k&7)*OUTD + n]
                     : mhb[(size_t)(k-64)*OUTD + n];
    }
    wfrag[idx] = f2bf(v);
}

// ---------- kernel 3d: PQ -> MFMA B-fragment layout (bf16) ----------
// K=582 pad 608 (19 steps), N=192 (12 tiles)
__global__ __launch_bounds__(256) void k_pqpack(
    const float* __restrict__ PQ, ushort* __restrict__ pqfrag)
{
    int idx = blockIdx.x*256 + threadIdx.x;
    const int total = 12*MIX_KS*64*8;   // 116736
    if (idx >= total) return;
    int j  = idx & 7;
    int l  = (idx >> 3) & 63;
    int tk = idx >> 9;             // tile*19 + kk
    int t  = tk / MIX_KS, kk = tk - t*MIX_KS;
    int k  = kk*32 + ((l>>4)<<3) + j;   // 0..607
    int n  = t*16 + (l & 15);           // 0..191
    float v = (k < 582) ? PQ[(size_t)k*HH + n] : 0.f;
    pqfrag[idx] = f2bf(v);
}

// ---------- kernel 4: filt MFMA GEMM (13792x80)x(80x1649) -> bf16 filt ----------
__global__ __launch_bounds__(256) void k_filt(
    const float* __restrict__ A, const ushort* __restrict__ wfrag,
    ushort* __restrict__ filt)
{
    __shared__ __align__(16) ushort Abf[16*104];   // stride 104: 2-way banks (free)
    int tid = threadIdx.x;
    int bc0 = blockIdx.x*16;
    for (int i = tid; i < 16*96; i += 256){
        int r = i/96, j = i - r*96;
        float v = (j < 80) ? A[(size_t)(bc0+r)*80 + j] : 0.f;
        Abf[r*104 + j] = f2bf(v);
    }
    __syncthreads();
    int wid = tid >> 6, lane = tid & 63;
    int lrow = lane & 15, lk8 = (lane >> 4) << 3, row0 = (lane >> 4)*4;
    bf16x8 a0 = *(const bf16x8*)&Abf[lrow*104 +  0 + lk8];
    bf16x8 a1 = *(const bf16x8*)&Abf[lrow*104 + 32 + lk8];
    bf16x8 a2 = *(const bf16x8*)&Abf[lrow*104 + 64 + lk8];
    for (int t = wid*26; t < wid*26 + 26; ++t){
        const ushort* wb = wfrag + (size_t)(t*3)*512 + lane*8;
        f32x4 acc = {0.f,0.f,0.f,0.f};
        acc = __builtin_amdgcn_mfma_f32_16x16x32_bf16(a0, *(const bf16x8*)(wb       ), acc, 0,0,0);
        acc = __builtin_amdgcn_mfma_f32_16x16x32_bf16(a1, *(const bf16x8*)(wb +  512), acc, 0,0,0);
        acc = __builtin_amdgcn_mfma_f32_16x16x32_bf16(a2, *(const bf16x8*)(wb + 1024), acc, 0,0,0);
        int n = t*16 + lrow;
        if (n < OUTD){
#pragma unroll
            for (int r = 0; r < 4; ++r)
                filt[(size_t)(bc0+row0+r)*OUTD + n] = f2bf(acc[r]);
        }
    }
}

// ---------- kernel 5: gather + MFMA DFT + filter apply -> bf16 mix_in ----------
__global__ __launch_bounds__(256) void k_dft(
    const float* __restrict__ win, const ushort* __restrict__ filtb,
    const float* __restrict__ w_sgn, const int* __restrict__ leader,
    const int* __restrict__ shiftp, const ushort* __restrict__ bfrag,
    ushort* __restrict__ mixin)
{
    __shared__ __align__(16) float raw[9][192];
    __shared__ __align__(16) ushort Ae[16*104];
    __shared__ __align__(16) ushort Ao[16*104];
    __shared__ float sfl[9][97][2];
    __shared__ float fl[OUTD];
    __shared__ int   rbase[9];
    __shared__ float rsgn[9];
    int bc = blockIdx.x;
    int tid = threadIdx.x;
    int b = bc / CC, c = bc - b*CC;
    if (tid < 9){
        int k = tid;
        int src_c = c, sh = 0; float sg = 1.f;
        if (k < 8){
            src_c = leader[(size_t)bc*8 + k];
            sh    = shiftp[(size_t)bc*8 + k];
            sg    = w_sgn[(size_t)bc*8 + k];
        }
        rbase[k] = (b*CC + src_c)*WINL + 47 - sh;
        rsgn[k]  = sg;
    }
    __syncthreads();
    for (int i = tid; i < 9*192; i += 256){
        int r = i / 192, hh = i - r*192;
        raw[r][hh] = win[(size_t)rbase[r] + hh] * rsgn[r];
    }
    for (int i = tid; i < OUTD; i += 256) fl[i] = bf2f(filtb[(size_t)bc*OUTD + i]);
    __syncthreads();
    for (int i = tid; i < 864; i += 256){
        int r = i/96, hh = i - r*96;
        float x0 = raw[r][hh], x1 = raw[r][hh+96];
        Ae[r*104+hh] = f2bf(x0 + x1);
        Ao[r*104+hh] = f2bf(x0 - x1);
    }
    __syncthreads();
    int wid = tid >> 6, lane = tid & 63;
    int lrow = lane & 15;
    int lk8  = (lane >> 4) << 3;
    for (int t = wid; t < 13; t += 4){
        const ushort* Ab = (t < 7) ? Ae : Ao;
        const ushort* bb = bfrag + (size_t)(t*3)*512;
        f32x4 acc = {0.f, 0.f, 0.f, 0.f};
#pragma unroll
        for (int kk = 0; kk < 3; ++kk){
            bf16x8 a = *(const bf16x8*)&Ab[lrow*104 + kk*32 + lk8];
            bf16x8 bfr = *(const bf16x8*)&bb[kk*512 + lane*8];
            acc = __builtin_amdgcn_mfma_f32_16x16x32_bf16(a, bfr, acc, 0, 0, 0);
        }
        int row0 = (lane >> 4) * 4;     // D: row=(lane>>4)*4+reg, col=lane&15  [m89]
#pragma unroll
        for (int r = 0; r < 4; ++r){
            int row = row0 + r;
            if (row <= 8){
                if (t < 7){
                    int n = t*16 + lrow;
                    if (n < 98) sfl[row][n - (n&1)][n&1] = acc[r];
                } else {
                    int n = (t-7)*16 + lrow;
                    sfl[row][n | 1][n&1] = acc[r];
                }
            }
        }
    }
    __syncthreads();
    if (tid < FREQ){
        int fr = tid;
        float yre = sfl[8][fr][0], yim = sfl[8][fr][1];
        float lre=0.f, lim=0.f, dre=0.f, dim_=0.f;
#pragma unroll
        for (int k=0;k<8;++k){
            float sre = sfl[k][fr][0], sim = sfl[k][fr][1];
            float f1 = fl[k*FREQ+fr], f2 = fl[(8+k)*FREQ+fr];
            lre = fmaf(sre, f1, lre);       lim  = fmaf(sim, f1, lim);
            dre = fmaf(sre-yre, f2, dre);   dim_ = fmaf(sim-yim, f2, dim_);
        }
        float f3 = fl[16*FREQ+fr];
        ushort* mrow = mixin + (size_t)bc*582;
        mrow[fr]           = f2bf(lre);
        mrow[97 + fr]      = f2bf(dre);
        mrow[194 + fr]     = f2bf(yre*f3);
        mrow[291 + fr]     = f2bf(lim);
        mrow[291+97 + fr]  = f2bf(dim_);
        mrow[291+194 + fr] = f2bf(yim*f3);
    }
}

// ---------- kernel 6: MFMA y_add GEMM (13792x582)x(582x192) + denorm + store ----------
__global__ __launch_bounds__(256) void k_mix(
    const ushort* __restrict__ mixin, const ushort* __restrict__ pqfrag,
    const float* __restrict__ cst, const float* __restrict__ win,
    const float* __restrict__ w_mu, const float* __restrict__ w_std,
    float* __restrict__ out)
{
    __shared__ __align__(16) ushort Abf[16*616];   // stride 616: 2-way banks
    int tid = threadIdx.x;
    int bc0 = blockIdx.x*16;
    for (int i = tid; i < 16*304; i += 256){
        int r = i/304, jc = i - r*304;     // uint column (2 ushorts)
        unsigned v = 0u;
        if (jc < 291) v = *(const unsigned*)&mixin[(size_t)(bc0+r)*582 + jc*2];
        *(unsigned*)&Abf[r*616 + jc*2] = v;
    }
    __syncthreads();
    int wid = tid >> 6, lane = tid & 63;
    int lrow = lane & 15, lk8 = (lane >> 4) << 3, row0 = (lane >> 4)*4;
    f32x4 acc0 = {0.f,0.f,0.f,0.f}, acc1 = {0.f,0.f,0.f,0.f}, acc2 = {0.f,0.f,0.f,0.f};
    const ushort* pq0 = pqfrag + (size_t)((wid*3+0)*MIX_KS)*512 + lane*8;
    const ushort* pq1 = pqfrag + (size_t)((wid*3+1)*MIX_KS)*512 + lane*8;
    const ushort* pq2 = pqfrag + (size_t)((wid*3+2)*MIX_KS)*512 + lane*8;
    for (int kk = 0; kk < MIX_KS; ++kk){
        bf16x8 a = *(const bf16x8*)&Abf[lrow*616 + kk*32 + lk8];
        acc0 = __builtin_amdgcn_mfma_f32_16x16x32_bf16(a, *(const bf16x8*)(pq0 + (size_t)kk*512), acc0, 0,0,0);
        acc1 = __builtin_amdgcn_mfma_f32_16x16x32_bf16(a, *(const bf16x8*)(pq1 + (size_t)kk*512), acc1, 0,0,0);
        acc2 = __builtin_amdgcn_mfma_f32_16x16x32_bf16(a, *(const bf16x8*)(pq2 + (size_t)kk*512), acc2, 0,0,0);
    }
#pragma unroll
    for (int tl = 0; tl < 3; ++tl){
        f32x4 acc = (tl==0) ? acc0 : ((tl==1) ? acc1 : acc2);
        int h = (wid*3 + tl)*16 + lrow;
        float cs = cst[h];
#pragma unroll
        for (int r = 0; r < 4; ++r){
            int bc = bc0 + row0 + r;
            int b = bc / CC, c = bc - b*CC;
            float yn = win[(size_t)bc*WINL + 47 + h];
            float v = (acc[r] + cs + yn)*w_std[bc] + w_mu[bc];
            out[((size_t)b*HH + h)*CC + c] = v;
        }
    }
}

extern "C" void kernel_launch(void* const* d_in, const int* in_sizes, int n_in,
                              void* d_out, int out_size, void* d_ws, size_t ws_size,
                              hipStream_t stream) {
    const float* x      = (const float*)d_in[0];
    const float* y      = (const float*)d_in[1];
    const float* r_in   = (const float*)d_in[2];
    const float* temp   = (const float*)d_in[3];
    const float* cw     = (const float*)d_in[4];
    const float* bstate = (const float*)d_in[5];
    const float* sbias  = (const float*)d_in[6];
    const float* mhw    = (const float*)d_in[7];
    const float* mhb    = (const float*)d_in[8];
    const float* wr     = (const float*)d_in[9];
    const float* wi     = (const float*)d_in[10];
    const float* br     = (const float*)d_in[11];
    const float* bi     = (const float*)d_in[12];
    const int*   leader = (const int*)d_in[13];
    const int*   shiftp = (const int*)d_in[14];
    float* ws  = (float*)d_ws;
    float* out = (float*)d_out;

    size_t o_win  = 0;
    size_t o_mu   = o_win  + (size_t)NBC*WINL;
    size_t o_std  = o_mu   + NBC;
    size_t o_istd = o_std  + NBC;
    size_t o_sgn  = o_istd + NBC;
    size_t o_A    = o_sgn  + (size_t)NBC*8;
    size_t o_filt = o_A    + (size_t)NBC*80;                  // ushort: NBC*OUTD -> /2 floats
    size_t o_mix  = o_filt + (size_t)NBC*OUTD/2;              // ushort: NBC*582 -> /2 floats
    size_t o_PQ   = o_mix  + (size_t)NBC*291;
    size_t o_cst  = o_PQ   + (size_t)582*HH;
    size_t o_bfr  = o_cst  + HH;                              // 19968 ushorts
    size_t o_wfr  = o_bfr  + 19968/2;                         // 159744 ushorts
    size_t o_pqf  = o_wfr  + 159744/2;                        // 116736 ushorts

    ushort* filtb  = (ushort*)(ws + o_filt);
    ushort* mixinb = (ushort*)(ws + o_mix);
    ushort* bfrag  = (ushort*)(ws + o_bfr);
    ushort* wfrag  = (ushort*)(ws + o_wfr);
    ushort* pqfrag = (ushort*)(ws + o_pqf);

    k_stats<<<dim3((NBC+63)/64), dim3(64), 0, stream>>>(
        x, r_in, temp, cw, bstate, sbias,
        ws+o_mu, ws+o_std, ws+o_istd, ws+o_sgn, ws+o_A);

    k_win<<<dim3(BB, 8, 27), dim3(32, 8), 0, stream>>>(
        x, y, ws+o_mu, ws+o_istd, ws+o_win);

    k_pq<<<dim3(HH), dim3(640), 0, stream>>>(
        wr, wi, br, bi, ws+o_PQ, ws+o_cst);

    k_bfrag<<<dim3(78), dim3(256), 0, stream>>>(bfrag);
    k_wpack<<<dim3((WT*3*64*8+255)/256), dim3(256), 0, stream>>>(mhw, mhb, wfrag);
    k_pqpack<<<dim3((12*MIX_KS*64*8+255)/256), dim3(256), 0, stream>>>(ws+o_PQ, pqfrag);

    k_filt<<<dim3(NBC/16), dim3(256), 0, stream>>>(ws+o_A, wfrag, filtb);

    k_dft<<<dim3(NBC), dim3(256), 0, stream>>>(
        ws+o_win, filtb, ws+o_sgn, leader, shiftp, bfrag, mixinb);

    k_mix<<<dim3(NBC/16), dim3(256), 0, stream>>>(
        mixinb, pqfrag, ws+o_cst, ws+o_win, ws+o_mu, ws+o_std, out);
}

// Round 12
// 249.362 us; speedup vs baseline: 2.1055x; 1.2427x over previous
//
#include <hip/hip_runtime.h>
#include <math.h>

#define BB 16
#define LL 336
#define HH 192
#define CC 862
#define KK 8
#define FREQ 97
#define OUTD 1649      // 17*97
#define OUTP 1664      // padded filt row stride (16B-aligned rows)
#define TTOT 528
#define WINL 240       // window covers t in [289, 528), 239 used + 1 pad
#define NBC (BB*CC)    // 13792
#define PI_F 3.14159265358979323846f
#define WT 104         // N-tiles in wfrag (1664 = 104*16)
#define MIX_KS 19      // K-steps in pqfrag (608 = 19*32)

typedef __attribute__((ext_vector_type(8))) short bf16x8;
typedef __attribute__((ext_vector_type(4))) float f32x4;

static __device__ __forceinline__ ushort f2bf(float f){
    unsigned u = __float_as_uint(f);
    unsigned r = (u + 0x7FFFu + ((u >> 16) & 1u)) >> 16;   // RNE
    return (ushort)r;
}
static __device__ __forceinline__ float bf2f(ushort u){
    return __uint_as_float(((unsigned)u) << 16);
}

// ---------- kernel 1: per-(b,c) stats + classifier softmax + A (4-way L-split) ----------
__global__ __launch_bounds__(256) void k_stats(
    const float* __restrict__ x, const float* __restrict__ r_in,
    const float* __restrict__ temp, const float* __restrict__ cw,
    const float* __restrict__ bstate, const float* __restrict__ sbias,
    float* __restrict__ w_mu, float* __restrict__ w_std, float* __restrict__ w_istd,
    float* __restrict__ w_sgn, float* __restrict__ w_A)
{
    __shared__ float red[4][64][10];
    int tid = threadIdx.x;
    int lane = tid & 63, q = tid >> 6;
    int bc = blockIdx.x*64 + lane;
    int b = bc / CC, c = bc - b*CC;
    float sum = 0.f, sq = 0.f, lg[8];
#pragma unroll
    for (int s=0;s<8;++s) lg[s]=0.f;
    if (bc < NBC){
        const float* xp = x + (size_t)b*LL*CC + c;
        int l0 = q*84;
        for (int l = l0; l < l0+84; ++l){
            float v = xp[(size_t)l*CC];
            sum += v; sq += v*v;
#pragma unroll
            for (int s=0;s<8;++s) lg[s] = fmaf(v, cw[s*LL+l], lg[s]);
        }
    }
    red[q][lane][0] = sum; red[q][lane][1] = sq;
#pragma unroll
    for (int s=0;s<8;++s) red[q][lane][2+s] = lg[s];
    __syncthreads();
    if (tid < 64 && bc < NBC){
        sum = 0.f; sq = 0.f;
#pragma unroll
        for (int s=0;s<8;++s) lg[s] = 0.f;
#pragma unroll
        for (int qq=0;qq<4;++qq){
            sum += red[qq][lane][0]; sq += red[qq][lane][1];
#pragma unroll
            for (int s=0;s<8;++s) lg[s] += red[qq][lane][2+s];
        }
        float mu   = sum * (1.f/LL);
        float var  = sq * (1.f/LL) - mu*mu;
        float stdv = sqrtf(var + 1e-8f);
        float istd = 1.f/stdv;
#pragma unroll
        for (int s=0;s<8;++s) lg[s] += sbias[s] + bstate[c*8+s];
        float m = lg[0];
#pragma unroll
        for (int s=1;s<8;++s) m = fmaxf(m, lg[s]);
        float p[8]; float den = 0.f;
#pragma unroll
        for (int s=0;s<8;++s){ p[s] = expf(lg[s]-m); den += p[s]; }
        float iden = 1.f/den;
#pragma unroll
        for (int s=0;s<8;++s) p[s] *= iden;

        float invT = 1.f / temp[0];
        float ek[8], sg[8];
        float dsum = expf(invT);
#pragma unroll
        for (int k=0;k<8;++k){
            float r = r_in[(size_t)bc*8 + k];
            sg[k] = (r > 0.f) ? 1.f : ((r < 0.f) ? -1.f : 0.f);
            ek[k] = expf(fabsf(r)*invT);
            dsum += ek[k];
        }
        float idsum = 1.f/dsum;

        w_mu[bc] = mu; w_std[bc] = stdv; w_istd[bc] = istd;
#pragma unroll
        for (int k=0;k<8;++k) w_sgn[(size_t)bc*8+k] = sg[k];
        float* Ar = w_A + (size_t)bc*80;
#pragma unroll
        for (int s=0;s<8;++s)
#pragma unroll
            for (int k=0;k<8;++k) Ar[s*8+k] = p[s]*(ek[k]*idsum);
#pragma unroll
        for (int s=0;s<8;++s) Ar[64+s] = p[s];
    }
}

// ---------- kernel 2: build normalized window seq_all[t in 289..527] (transposed) ----------
__global__ __launch_bounds__(256) void k_win(
    const float* __restrict__ x, const float* __restrict__ y,
    const float* __restrict__ w_mu, const float* __restrict__ w_istd,
    float* __restrict__ win)
{
    __shared__ float buf[32][33];
    int b  = blockIdx.x;
    int t0 = blockIdx.y*32;
    int c0 = blockIdx.z*32;
    int tx = threadIdx.x, ty = threadIdx.y;   // 32 x 8
#pragma unroll
    for (int i=0;i<4;++i){
        int tl = ty + i*8;
        int t  = 289 + t0 + tl;
        int c  = c0 + tx;
        float v = 0.f;
        if (t < TTOT && c < CC){
            float raw = (t < LL) ? x[((size_t)b*LL + t)*CC + c]
                                 : y[((size_t)b*HH + (t-LL))*CC + c];
            int bc = b*CC + c;
            v = (raw - w_mu[bc]) * w_istd[bc];
        }
        buf[tl][tx] = v;
    }
    __syncthreads();
#pragma unroll
    for (int i=0;i<4;++i){
        int cl = ty + i*8;
        int c  = c0 + cl;
        int wl = t0 + tx;
        if (wl < 239 && c < CC)
            win[(size_t)(b*CC + c)*WINL + wl] = buf[tx][cl];
    }
}

// ---------- kernel 3: combined (w_c then irfft) real matrix PQ[582][192] + cst ----------
__global__ __launch_bounds__(640) void k_pq(
    const float* __restrict__ wr, const float* __restrict__ wi,
    const float* __restrict__ br, const float* __restrict__ bi,
    float* __restrict__ PQ, float* __restrict__ cst)
{
    int h = blockIdx.x;
    int tid = threadIdx.x;
    __shared__ float a_s[97], b_s[97], t_s[97];
    if (tid < 97){
        int o = tid;
        int mmod = (o*h) % 192;
        float th = (2.f*PI_F/192.f) * (float)mmod;
        float sn, cs; sincosf(th, &sn, &cs);
        float aa, bb;
        if (o == 0)      { aa = 1.f/192.f;                      bb = 0.f; }
        else if (o == 96){ aa = ((h&1)? -1.f:1.f)/192.f;        bb = 0.f; }
        else             { aa = 2.f*cs/192.f;                   bb = -2.f*sn/192.f; }
        a_s[o]=aa; b_s[o]=bb;
        t_s[o] = aa*br[o] + bb*bi[o];
    }
    __syncthreads();
    if (tid < 582){
        int j = tid;
        int isP = (j < 291);
        int jj = isP ? j : j-291;
        float acc = 0.f;
        for (int o=0;o<97;++o){
            float wrv = wr[o*291+jj], wiv = wi[o*291+jj];
            acc += isP ? (a_s[o]*wrv + b_s[o]*wiv)
                       : (b_s[o]*wrv - a_s[o]*wiv);
        }
        PQ[(size_t)j*HH + h] = acc;
    }
    if (tid == 0){
        float s = 0.f;
        for (int o=0;o<97;++o) s += t_s[o];
        cst[h] = s;
    }
}

// ---------- kernel 3b: DFT matrix in MFMA B-fragment layout (bf16) ----------
__global__ __launch_bounds__(256) void k_bfrag(ushort* __restrict__ bfrag)
{
    int idx = blockIdx.x*256 + threadIdx.x;
    const int total = 13*3*64*8;   // 19968
    if (idx >= total) return;
    int j  = idx & 7;
    int l  = (idx >> 3) & 63;
    int tk = idx >> 9;             // tile*3 + kk
    int t  = tk / 3, kk = tk - t*3;
    int k  = kk*32 + ((l>>4)<<3) + j;
    int nl = l & 15;
    float v = 0.f;
    if (t < 7){
        int n = t*16 + nl;
        if (n < 98){
            int g  = n >> 1;
            int mm = (g*k) % 96;
            float th = (2.f*PI_F/96.f)*(float)mm;
            float sn, cs; sincosf(th, &sn, &cs);
            v = (n & 1) ? -sn : cs;
        }
    } else {
        int n = (t-7)*16 + nl;
        int f = n | 1;
        int mm = (f*k) % 192;
        float th = (2.f*PI_F/192.f)*(float)mm;
        float sn, cs; sincosf(th, &sn, &cs);
        v = (n & 1) ? -sn : cs;
    }
    bfrag[idx] = f2bf(v);
}

// ---------- kernel 3c: mix_head weights -> MFMA B-fragment layout (bf16) ----------
__global__ __launch_bounds__(256) void k_wpack(
    const float* __restrict__ mhw, const float* __restrict__ mhb,
    ushort* __restrict__ wfrag)
{
    int idx = blockIdx.x*256 + threadIdx.x;
    const int total = WT*3*64*8;   // 159744
    if (idx >= total) return;
    int j  = idx & 7;
    int l  = (idx >> 3) & 63;
    int tk = idx >> 9;             // tile*3 + kk
    int t  = tk / 3, kk = tk - t*3;
    int k  = kk*32 + ((l>>4)<<3) + j;   // 0..95
    int n  = t*16 + (l & 15);           // 0..1663
    float v = 0.f;
    if (n < OUTD && k < 80){
        v = (k < 64) ? mhw[(size_t)(k>>3)*(8*OUTD) + (size_t)(k&7)*OUTD + n]
                     : mhb[(size_t)(k-64)*OUTD + n];
    }
    wfrag[idx] = f2bf(v);
}

// ---------- kernel 3d: PQ -> MFMA B-fragment layout (bf16) ----------
__global__ __launch_bounds__(256) void k_pqpack(
    const float* __restrict__ PQ, ushort* __restrict__ pqfrag)
{
    int idx = blockIdx.x*256 + threadIdx.x;
    const int total = 12*MIX_KS*64*8;   // 116736
    if (idx >= total) return;
    int j  = idx & 7;
    int l  = (idx >> 3) & 63;
    int tk = idx >> 9;             // tile*19 + kk
    int t  = tk / MIX_KS, kk = tk - t*MIX_KS;
    int k  = kk*32 + ((l>>4)<<3) + j;   // 0..607
    int n  = t*16 + (l & 15);           // 0..191
    float v = (k < 582) ? PQ[(size_t)k*HH + n] : 0.f;
    pqfrag[idx] = f2bf(v);
}

// ---------- kernel 4: filt MFMA GEMM (13792x80)x(80x1649) -> bf16 filt (stride OUTP) ----------
__global__ __launch_bounds__(256) void k_filt(
    const float* __restrict__ A, const ushort* __restrict__ wfrag,
    ushort* __restrict__ filt)
{
    __shared__ __align__(16) ushort Abf[16*104];
    int tid = threadIdx.x;
    int bc0 = blockIdx.x*16;
    for (int i = tid; i < 16*96; i += 256){
        int r = i/96, j = i - r*96;
        float v = (j < 80) ? A[(size_t)(bc0+r)*80 + j] : 0.f;
        Abf[r*104 + j] = f2bf(v);
    }
    __syncthreads();
    int wid = tid >> 6, lane = tid & 63;
    int lrow = lane & 15, lk8 = (lane >> 4) << 3, row0 = (lane >> 4)*4;
    bf16x8 a0 = *(const bf16x8*)&Abf[lrow*104 +  0 + lk8];
    bf16x8 a1 = *(const bf16x8*)&Abf[lrow*104 + 32 + lk8];
    bf16x8 a2 = *(const bf16x8*)&Abf[lrow*104 + 64 + lk8];
    for (int t = wid*26; t < wid*26 + 26; ++t){
        const ushort* wb = wfrag + (size_t)(t*3)*512 + lane*8;
        f32x4 acc = {0.f,0.f,0.f,0.f};
        acc = __builtin_amdgcn_mfma_f32_16x16x32_bf16(a0, *(const bf16x8*)(wb       ), acc, 0,0,0);
        acc = __builtin_amdgcn_mfma_f32_16x16x32_bf16(a1, *(const bf16x8*)(wb +  512), acc, 0,0,0);
        acc = __builtin_amdgcn_mfma_f32_16x16x32_bf16(a2, *(const bf16x8*)(wb + 1024), acc, 0,0,0);
        int n = t*16 + lrow;
        if (n < OUTD){
#pragma unroll
            for (int r = 0; r < 4; ++r)
                filt[(size_t)(bc0+row0+r)*OUTP + n] = f2bf(acc[r]);
        }
    }
}

// ---------- kernel 5: gather + MFMA DFT + filter apply -> bf16 mix_in ----------
__global__ __launch_bounds__(256) void k_dft(
    const float* __restrict__ win, const ushort* __restrict__ filtb,
    const float* __restrict__ w_sgn, const int* __restrict__ leader,
    const int* __restrict__ shiftp, const ushort* __restrict__ bfrag,
    ushort* __restrict__ mixin)
{
    __shared__ __align__(16) ushort Ae[16*104];
    __shared__ __align__(16) ushort Ao[16*104];
    __shared__ float sfl[2][9][97];       // [reim][row][freq]: stride-1 epilogue reads
    __shared__ __align__(4) ushort flu[OUTP];
    __shared__ int   rbase[9];
    __shared__ float rsgn[9];
    int bc = blockIdx.x;
    int tid = threadIdx.x;
    int b = bc / CC, c = bc - b*CC;
    if (tid < 9){
        int k = tid;
        int src_c = c, sh = 0; float sg = 1.f;
        if (k < 8){
            src_c = leader[(size_t)bc*8 + k];
            sh    = shiftp[(size_t)bc*8 + k];
            sg    = w_sgn[(size_t)bc*8 + k];
        }
        rbase[k] = (b*CC + src_c)*WINL + 47 - sh;
        rsgn[k]  = sg;
    }
    // stage filt row (bf16, dword copies, conflict-free)
    for (int i = tid; i < OUTP/2; i += 256)
        *(unsigned*)&flu[i*2] = *(const unsigned*)&filtb[(size_t)bc*OUTP + i*2];
    __syncthreads();
    // fold h/h+96 directly from global -> bf16 MFMA A layout
    for (int i = tid; i < 864; i += 256){
        int r = i/96, hh = i - r*96;
        const float* wp = win + (size_t)rbase[r];
        float sg = rsgn[r];
        float x0 = wp[hh]*sg, x1 = wp[hh+96]*sg;
        Ae[r*104+hh] = f2bf(x0 + x1);
        Ao[r*104+hh] = f2bf(x0 - x1);
    }
    __syncthreads();
    int wid = tid >> 6, lane = tid & 63;
    int lrow = lane & 15;
    int lk8  = (lane >> 4) << 3;
    int row0 = (lane >> 4) * 4;
    for (int t = wid; t < 13; t += 4){
        const ushort* Ab = (t < 7) ? Ae : Ao;
        const ushort* bb = bfrag + (size_t)(t*3)*512 + lane*8;
        f32x4 acc = {0.f, 0.f, 0.f, 0.f};
#pragma unroll
        for (int kk = 0; kk < 3; ++kk){
            bf16x8 a = *(const bf16x8*)&Ab[lrow*104 + kk*32 + lk8];
            acc = __builtin_amdgcn_mfma_f32_16x16x32_bf16(a, *(const bf16x8*)(bb + kk*512), acc, 0, 0, 0);
        }
#pragma unroll
        for (int r = 0; r < 4; ++r){
            int row = row0 + r;
            if (row <= 8){
                if (t < 7){
                    int n = t*16 + lrow;
                    if (n < 98) sfl[n & 1][row][n & ~1] = acc[r];
                } else {
                    int n = (t-7)*16 + lrow;
                    sfl[n & 1][row][n | 1] = acc[r];
                }
            }
        }
    }
    __syncthreads();
    if (tid < 194){
        int p = (tid >= 97) ? 1 : 0;
        int fr = tid - 97*p;
        float yv = sfl[p][8][fr];
        float ls = 0.f, ds = 0.f;
#pragma unroll
        for (int k=0;k<8;++k){
            float sv = sfl[p][k][fr];
            float f1 = bf2f(flu[k*FREQ+fr]), f2 = bf2f(flu[(8+k)*FREQ+fr]);
            ls = fmaf(sv, f1, ls);
            ds = fmaf(sv - yv, f2, ds);
        }
        float f3 = bf2f(flu[16*FREQ+fr]);
        ushort* mrow = mixin + (size_t)bc*582 + p*291;
        mrow[fr]       = f2bf(ls);
        mrow[97 + fr]  = f2bf(ds);
        mrow[194 + fr] = f2bf(yv*f3);
    }
}

// ---------- kernel 6: MFMA y_add GEMM (13792x582)x(582x192) + denorm + store ----------
__global__ __launch_bounds__(256) void k_mix(
    const ushort* __restrict__ mixin, const ushort* __restrict__ pqfrag,
    const float* __restrict__ cst, const float* __restrict__ win,
    const float* __restrict__ w_mu, const float* __restrict__ w_std,
    float* __restrict__ out)
{
    __shared__ __align__(16) ushort Abf[16*616];
    int tid = threadIdx.x;
    int bc0 = blockIdx.x*16;
    for (int i = tid; i < 16*304; i += 256){
        int r = i/304, jc = i - r*304;
        unsigned v = 0u;
        if (jc < 291) v = *(const unsigned*)&mixin[(size_t)(bc0+r)*582 + jc*2];
        *(unsigned*)&Abf[r*616 + jc*2] = v;
    }
    __syncthreads();
    int wid = tid >> 6, lane = tid & 63;
    int lrow = lane & 15, lk8 = (lane >> 4) << 3, row0 = (lane >> 4)*4;
    f32x4 acc0 = {0.f,0.f,0.f,0.f}, acc1 = {0.f,0.f,0.f,0.f}, acc2 = {0.f,0.f,0.f,0.f};
    const ushort* pq0 = pqfrag + (size_t)((wid*3+0)*MIX_KS)*512 + lane*8;
    const ushort* pq1 = pqfrag + (size_t)((wid*3+1)*MIX_KS)*512 + lane*8;
    const ushort* pq2 = pqfrag + (size_t)((wid*3+2)*MIX_KS)*512 + lane*8;
    for (int kk = 0; kk < MIX_KS; ++kk){
        bf16x8 a = *(const bf16x8*)&Abf[lrow*616 + kk*32 + lk8];
        acc0 = __builtin_amdgcn_mfma_f32_16x16x32_bf16(a, *(const bf16x8*)(pq0 + (size_t)kk*512), acc0, 0,0,0);
        acc1 = __builtin_amdgcn_mfma_f32_16x16x32_bf16(a, *(const bf16x8*)(pq1 + (size_t)kk*512), acc1, 0,0,0);
        acc2 = __builtin_amdgcn_mfma_f32_16x16x32_bf16(a, *(const bf16x8*)(pq2 + (size_t)kk*512), acc2, 0,0,0);
    }
#pragma unroll
    for (int tl = 0; tl < 3; ++tl){
        f32x4 acc = (tl==0) ? acc0 : ((tl==1) ? acc1 : acc2);
        int h = (wid*3 + tl)*16 + lrow;
        float cs = cst[h];
#pragma unroll
        for (int r = 0; r < 4; ++r){
            int bc = bc0 + row0 + r;
            int b = bc / CC, c = bc - b*CC;
            float yn = win[(size_t)bc*WINL + 47 + h];
            float v = (acc[r] + cs + yn)*w_std[bc] + w_mu[bc];
            out[((size_t)b*HH + h)*CC + c] = v;
        }
    }
}

extern "C" void kernel_launch(void* const* d_in, const int* in_sizes, int n_in,
                              void* d_out, int out_size, void* d_ws, size_t ws_size,
                              hipStream_t stream) {
    const float* x      = (const float*)d_in[0];
    const float* y      = (const float*)d_in[1];
    const float* r_in   = (const float*)d_in[2];
    const float* temp   = (const float*)d_in[3];
    const float* cw     = (const float*)d_in[4];
    const float* bstate = (const float*)d_in[5];
    const float* sbias  = (const float*)d_in[6];
    const float* mhw    = (const float*)d_in[7];
    const float* mhb    = (const float*)d_in[8];
    const float* wr     = (const float*)d_in[9];
    const float* wi     = (const float*)d_in[10];
    const float* br     = (const float*)d_in[11];
    const float* bi     = (const float*)d_in[12];
    const int*   leader = (const int*)d_in[13];
    const int*   shiftp = (const int*)d_in[14];
    float* ws  = (float*)d_ws;
    float* out = (float*)d_out;

    size_t o_win  = 0;
    size_t o_mu   = o_win  + (size_t)NBC*WINL;
    size_t o_std  = o_mu   + NBC;
    size_t o_istd = o_std  + NBC;
    size_t o_sgn  = o_istd + NBC;
    size_t o_A    = o_sgn  + (size_t)NBC*8;
    size_t o_filt = o_A    + (size_t)NBC*80;                  // ushort buf: NBC*OUTP/2 floats
    size_t o_mix  = o_filt + (size_t)NBC*OUTP/2;              // ushort buf: NBC*582/2 floats
    size_t o_PQ   = o_mix  + (size_t)NBC*291;
    size_t o_cst  = o_PQ   + (size_t)582*HH;
    size_t o_bfr  = o_cst  + HH;                              // 19968 ushorts
    size_t o_wfr  = o_bfr  + 19968/2;                         // 159744 ushorts
    size_t o_pqf  = o_wfr  + 159744/2;                        // 116736 ushorts

    ushort* filtb  = (ushort*)(ws + o_filt);
    ushort* mixinb = (ushort*)(ws + o_mix);
    ushort* bfrag  = (ushort*)(ws + o_bfr);
    ushort* wfrag  = (ushort*)(ws + o_wfr);
    ushort* pqfrag = (ushort*)(ws + o_pqf);

    k_stats<<<dim3((NBC+63)/64), dim3(256), 0, stream>>>(
        x, r_in, temp, cw, bstate, sbias,
        ws+o_mu, ws+o_std, ws+o_istd, ws+o_sgn, ws+o_A);

    k_win<<<dim3(BB, 8, 27), dim3(32, 8), 0, stream>>>(
        x, y, ws+o_mu, ws+o_istd, ws+o_win);

    k_pq<<<dim3(HH), dim3(640), 0, stream>>>(
        wr, wi, br, bi, ws+o_PQ, ws+o_cst);

    k_bfrag<<<dim3(78), dim3(256), 0, stream>>>(bfrag);
    k_wpack<<<dim3((WT*3*64*8+255)/256), dim3(256), 0, stream>>>(mhw, mhb, wfrag);
    k_pqpack<<<dim3((12*MIX_KS*64*8+255)/256), dim3(256), 0, stream>>>(ws+o_PQ, pqfrag);

    k_filt<<<dim3(NBC/16), dim3(256), 0, stream>>>(ws+o_A, wfrag, filtb);

    k_dft<<<dim3(NBC), dim3(256), 0, stream>>>(
        ws+o_win, filtb, ws+o_sgn, leader, shiftp, bfrag, mixinb);

    k_mix<<<dim3(NBC/16), dim3(256), 0, stream>>>(
        mixinb, pqfrag, ws+o_cst, ws+o_win, ws+o_mu, ws+o_std, out);
}

// Round 14
// 229.712 us; speedup vs baseline: 2.2856x; 1.0855x over previous
//
#include <hip/hip_runtime.h>
#include <hip/hip_bf16.h>
#include <math.h>

#define BB 16
#define LL 336
#define HH 192
#define CC 862
#define KK 8
#define FREQ 97
#define OUTD 1649      // 17*97
#define OUTP 1664      // padded filt row stride (16B-aligned rows)
#define TTOT 528
#define WINL 240       // window covers t in [289, 528), 239 used + 1 pad
#define NBC (BB*CC)    // 13792
#define PI_F 3.14159265358979323846f
#define WT 104         // N-tiles in wfrag (1664 = 104*16)
#define MIX_KS 19      // K-steps in pqfrag (608 = 19*32)
#define SFP 104        // sfl padded row stride

typedef __attribute__((ext_vector_type(8))) short bf16x8;
typedef __attribute__((ext_vector_type(4))) float f32x4;

static __device__ __forceinline__ ushort f2bf(float f){
    unsigned u = __float_as_uint(f);
    unsigned r = (u + 0x7FFFu + ((u >> 16) & 1u)) >> 16;   // RNE
    return (ushort)r;
}
static __device__ __forceinline__ float bf2f(ushort u){
    return __uint_as_float(((unsigned)u) << 16);
}

// ---------- kernel 1: per-(b,c) stats + classifier softmax + A (8-way L-split) ----------
__global__ __launch_bounds__(512) void k_stats(
    const float* __restrict__ x, const float* __restrict__ r_in,
    const float* __restrict__ temp, const float* __restrict__ cw,
    const float* __restrict__ bstate, const float* __restrict__ sbias,
    float* __restrict__ w_mu, float* __restrict__ w_std, float* __restrict__ w_istd,
    float* __restrict__ w_sgn, float* __restrict__ w_A)
{
    __shared__ float red[8][64][10];
    int tid = threadIdx.x;
    int lane = tid & 63, q = tid >> 6;
    int bc = blockIdx.x*64 + lane;
    int b = bc / CC, c = bc - b*CC;
    float sum = 0.f, sq = 0.f, lg[8];
#pragma unroll
    for (int s=0;s<8;++s) lg[s]=0.f;
    if (bc < NBC){
        const float* xp = x + (size_t)b*LL*CC + c;
        int l0 = q*42;
        for (int l = l0; l < l0+42; ++l){
            float v = xp[(size_t)l*CC];
            sum += v; sq += v*v;
#pragma unroll
            for (int s=0;s<8;++s) lg[s] = fmaf(v, cw[s*LL+l], lg[s]);
        }
    }
    red[q][lane][0] = sum; red[q][lane][1] = sq;
#pragma unroll
    for (int s=0;s<8;++s) red[q][lane][2+s] = lg[s];
    __syncthreads();
    if (tid < 64 && bc < NBC){
        sum = 0.f; sq = 0.f;
#pragma unroll
        for (int s=0;s<8;++s) lg[s] = 0.f;
#pragma unroll
        for (int qq=0;qq<8;++qq){
            sum += red[qq][lane][0]; sq += red[qq][lane][1];
#pragma unroll
            for (int s=0;s<8;++s) lg[s] += red[qq][lane][2+s];
        }
        float mu   = sum * (1.f/LL);
        float var  = sq * (1.f/LL) - mu*mu;
        float stdv = sqrtf(var + 1e-8f);
        float istd = 1.f/stdv;
#pragma unroll
        for (int s=0;s<8;++s) lg[s] += sbias[s] + bstate[c*8+s];
        float m = lg[0];
#pragma unroll
        for (int s=1;s<8;++s) m = fmaxf(m, lg[s]);
        float p[8]; float den = 0.f;
#pragma unroll
        for (int s=0;s<8;++s){ p[s] = expf(lg[s]-m); den += p[s]; }
        float iden = 1.f/den;
#pragma unroll
        for (int s=0;s<8;++s) p[s] *= iden;

        float invT = 1.f / temp[0];
        float ek[8], sg[8];
        float dsum = expf(invT);
#pragma unroll
        for (int k=0;k<8;++k){
            float r = r_in[(size_t)bc*8 + k];
            sg[k] = (r > 0.f) ? 1.f : ((r < 0.f) ? -1.f : 0.f);
            ek[k] = expf(fabsf(r)*invT);
            dsum += ek[k];
        }
        float idsum = 1.f/dsum;

        w_mu[bc] = mu; w_std[bc] = stdv; w_istd[bc] = istd;
#pragma unroll
        for (int k=0;k<8;++k) w_sgn[(size_t)bc*8+k] = sg[k];
        float* Ar = w_A + (size_t)bc*80;
#pragma unroll
        for (int s=0;s<8;++s)
#pragma unroll
            for (int k=0;k<8;++k) Ar[s*8+k] = p[s]*(ek[k]*idsum);
#pragma unroll
        for (int s=0;s<8;++s) Ar[64+s] = p[s];
    }
}

// ---------- kernel 2: build normalized window seq_all[t in 289..527] (transposed) ----------
__global__ __launch_bounds__(256) void k_win(
    const float* __restrict__ x, const float* __restrict__ y,
    const float* __restrict__ w_mu, const float* __restrict__ w_istd,
    float* __restrict__ win)
{
    __shared__ float buf[32][33];
    int b  = blockIdx.x;
    int t0 = blockIdx.y*32;
    int c0 = blockIdx.z*32;
    int tx = threadIdx.x, ty = threadIdx.y;   // 32 x 8
#pragma unroll
    for (int i=0;i<4;++i){
        int tl = ty + i*8;
        int t  = 289 + t0 + tl;
        int c  = c0 + tx;
        float v = 0.f;
        if (t < TTOT && c < CC){
            float raw = (t < LL) ? x[((size_t)b*LL + t)*CC + c]
                                 : y[((size_t)b*HH + (t-LL))*CC + c];
            int bc = b*CC + c;
            v = (raw - w_mu[bc]) * w_istd[bc];
        }
        buf[tl][tx] = v;
    }
    __syncthreads();
#pragma unroll
    for (int i=0;i<4;++i){
        int cl = ty + i*8;
        int c  = c0 + cl;
        int wl = t0 + tx;
        if (wl < 239 && c < CC)
            win[(size_t)(b*CC + c)*WINL + wl] = buf[tx][cl];
    }
}

// ---------- kernel 3: combined (w_c then irfft) real matrix PQ[582][192] + cst ----------
__global__ __launch_bounds__(640) void k_pq(
    const float* __restrict__ wr, const float* __restrict__ wi,
    const float* __restrict__ br, const float* __restrict__ bi,
    float* __restrict__ PQ, float* __restrict__ cst)
{
    int h = blockIdx.x;
    int tid = threadIdx.x;
    __shared__ float a_s[97], b_s[97], t_s[97];
    if (tid < 97){
        int o = tid;
        int mmod = (o*h) % 192;
        float th = (2.f*PI_F/192.f) * (float)mmod;
        float sn, cs; sincosf(th, &sn, &cs);
        float aa, bb;
        if (o == 0)      { aa = 1.f/192.f;                      bb = 0.f; }
        else if (o == 96){ aa = ((h&1)? -1.f:1.f)/192.f;        bb = 0.f; }
        else             { aa = 2.f*cs/192.f;                   bb = -2.f*sn/192.f; }
        a_s[o]=aa; b_s[o]=bb;
        t_s[o] = aa*br[o] + bb*bi[o];
    }
    __syncthreads();
    if (tid < 582){
        int j = tid;
        int isP = (j < 291);
        int jj = isP ? j : j-291;
        float acc = 0.f;
        for (int o=0;o<97;++o){
            float wrv = wr[o*291+jj], wiv = wi[o*291+jj];
            acc += isP ? (a_s[o]*wrv + b_s[o]*wiv)
                       : (b_s[o]*wrv - a_s[o]*wiv);
        }
        PQ[(size_t)j*HH + h] = acc;
    }
    if (tid == 0){
        float s = 0.f;
        for (int o=0;o<97;++o) s += t_s[o];
        cst[h] = s;
    }
}

// ---------- kernel 3b: ALL fragment packs in one launch ----------
// range 0: bfrag (19968), range 1: wfrag (159744), range 2: pqfrag (116736)
#define NBFR (13*3*64*8)
#define NWFR (WT*3*64*8)
#define NPQF (12*MIX_KS*64*8)
__global__ __launch_bounds__(256) void k_pack(
    const float* __restrict__ mhw, const float* __restrict__ mhb,
    const float* __restrict__ PQ,
    ushort* __restrict__ bfrag, ushort* __restrict__ wfrag, ushort* __restrict__ pqfrag)
{
    int gidx = blockIdx.x*256 + threadIdx.x;
    if (gidx < NBFR){
        int idx = gidx;
        int j  = idx & 7;
        int l  = (idx >> 3) & 63;
        int tk = idx >> 9;
        int t  = tk / 3, kk = tk - t*3;
        int k  = kk*32 + ((l>>4)<<3) + j;
        int nl = l & 15;
        float v = 0.f;
        if (t < 7){
            int n = t*16 + nl;
            if (n < 98){
                int g  = n >> 1;
                int mm = (g*k) % 96;
                float th = (2.f*PI_F/96.f)*(float)mm;
                float sn, cs; sincosf(th, &sn, &cs);
                v = (n & 1) ? -sn : cs;
            }
        } else {
            int n = (t-7)*16 + nl;
            int f = n | 1;
            int mm = (f*k) % 192;
            float th = (2.f*PI_F/192.f)*(float)mm;
            float sn, cs; sincosf(th, &sn, &cs);
            v = (n & 1) ? -sn : cs;
        }
        bfrag[idx] = f2bf(v);
    } else if (gidx < NBFR + NWFR){
        int idx = gidx - NBFR;
        int j  = idx & 7;
        int l  = (idx >> 3) & 63;
        int tk = idx >> 9;
        int t  = tk / 3, kk = tk - t*3;
        int k  = kk*32 + ((l>>4)<<3) + j;
        int n  = t*16 + (l & 15);
        float v = 0.f;
        if (n < OUTD && k < 80){
            v = (k < 64) ? mhw[(size_t)(k>>3)*(8*OUTD) + (size_t)(k&7)*OUTD + n]
                         : mhb[(size_t)(k-64)*OUTD + n];
        }
        wfrag[idx] = f2bf(v);
    } else if (gidx < NBFR + NWFR + NPQF){
        int idx = gidx - NBFR - NWFR;
        int j  = idx & 7;
        int l  = (idx >> 3) & 63;
        int tk = idx >> 9;
        int t  = tk / MIX_KS, kk = tk - t*MIX_KS;
        int k  = kk*32 + ((l>>4)<<3) + j;
        int n  = t*16 + (l & 15);
        float v = (k < 582) ? PQ[(size_t)k*HH + n] : 0.f;
        pqfrag[idx] = f2bf(v);
    }
}

// ---------- kernel 4: filt MFMA GEMM (13792x80)x(80x1649) -> bf16 filt (stride OUTP) ----------
__global__ __launch_bounds__(256) void k_filt(
    const float* __restrict__ A, const ushort* __restrict__ wfrag,
    ushort* __restrict__ filt)
{
    __shared__ __align__(16) ushort Abf[16*104];
    int tid = threadIdx.x;
    int bc0 = blockIdx.x*16;
    for (int i = tid; i < 16*96; i += 256){
        int r = i/96, j = i - r*96;
        float v = (j < 80) ? A[(size_t)(bc0+r)*80 + j] : 0.f;
        Abf[r*104 + j] = f2bf(v);
    }
    __syncthreads();
    int wid = tid >> 6, lane = tid & 63;
    int lrow = lane & 15, lk8 = (lane >> 4) << 3, row0 = (lane >> 4)*4;
    bf16x8 a0 = *(const bf16x8*)&Abf[lrow*104 +  0 + lk8];
    bf16x8 a1 = *(const bf16x8*)&Abf[lrow*104 + 32 + lk8];
    bf16x8 a2 = *(const bf16x8*)&Abf[lrow*104 + 64 + lk8];
    for (int t = wid*26; t < wid*26 + 26; ++t){
        const ushort* wb = wfrag + (size_t)(t*3)*512 + lane*8;
        f32x4 acc = {0.f,0.f,0.f,0.f};
        acc = __builtin_amdgcn_mfma_f32_16x16x32_bf16(a0, *(const bf16x8*)(wb       ), acc, 0,0,0);
        acc = __builtin_amdgcn_mfma_f32_16x16x32_bf16(a1, *(const bf16x8*)(wb +  512), acc, 0,0,0);
        acc = __builtin_amdgcn_mfma_f32_16x16x32_bf16(a2, *(const bf16x8*)(wb + 1024), acc, 0,0,0);
        int n = t*16 + lrow;
        if (n < OUTD){
#pragma unroll
            for (int r = 0; r < 4; ++r)
                filt[(size_t)(bc0+row0+r)*OUTP + n] = f2bf(acc[r]);
        }
    }
}

// ---------- kernel 5: gather + MFMA DFT + filter apply -> bf16 mix_in ----------
__global__ __launch_bounds__(256) void k_dft(
    const float* __restrict__ win, const ushort* __restrict__ filtb,
    const float* __restrict__ w_sgn, const int* __restrict__ leader,
    const int* __restrict__ shiftp, const ushort* __restrict__ bfrag,
    ushort* __restrict__ mixin)
{
    __shared__ __align__(16) ushort Ae[16*104];
    __shared__ __align__(16) ushort Ao[16*104];
    __shared__ float sfl[2][9][SFP];       // padded stride 104: 2-way banks (free)
    __shared__ int   rbase[9];
    __shared__ float rsgn[9];
    int bc = blockIdx.x;
    int tid = threadIdx.x;
    int b = bc / CC, c = bc - b*CC;
    if (tid < 9){
        int k = tid;
        int src_c = c, sh = 0; float sg = 1.f;
        if (k < 8){
            src_c = leader[(size_t)bc*8 + k];
            sh    = shiftp[(size_t)bc*8 + k];
            sg    = w_sgn[(size_t)bc*8 + k];
        }
        rbase[k] = (b*CC + src_c)*WINL + 47 - sh;
        rsgn[k]  = sg;
    }
    __syncthreads();
    // fold h/h+96 (pairs) -> packed bf16 dword writes into MFMA A layout
    for (int u = tid; u < 432; u += 256){
        int r = u/48, jj = u - r*48;
        int hh = 2*jj;
        const float* wp = win + (size_t)rbase[r];
        float sg = rsgn[r];
        float x00 = wp[hh]*sg,    x01 = wp[hh+1]*sg;
        float x10 = wp[hh+96]*sg, x11 = wp[hh+97]*sg;
        __hip_bfloat162 se = __float22bfloat162_rn(float2{x00+x10, x01+x11});
        __hip_bfloat162 so = __float22bfloat162_rn(float2{x00-x10, x01-x11});
        *(__hip_bfloat162*)&Ae[r*104+hh] = se;
        *(__hip_bfloat162*)&Ao[r*104+hh] = so;
    }
    __syncthreads();
    int wid = tid >> 6, lane = tid & 63;
    int lrow = lane & 15;
    int lk8  = (lane >> 4) << 3;
    int row0 = (lane >> 4) * 4;
    for (int t = wid; t < 13; t += 4){
        const ushort* Ab = (t < 7) ? Ae : Ao;
        const ushort* bb = bfrag + (size_t)(t*3)*512 + lane*8;
        f32x4 acc = {0.f, 0.f, 0.f, 0.f};
#pragma unroll
        for (int kk = 0; kk < 3; ++kk){
            bf16x8 a = *(const bf16x8*)&Ab[lrow*104 + kk*32 + lk8];
            acc = __builtin_amdgcn_mfma_f32_16x16x32_bf16(a, *(const bf16x8*)(bb + kk*512), acc, 0, 0, 0);
        }
#pragma unroll
        for (int r = 0; r < 4; ++r){
            int row = row0 + r;
            if (row <= 8){
                if (t < 7){
                    int n = t*16 + lrow;
                    if (n < 98) sfl[n & 1][row][n & ~1] = acc[r];
                } else {
                    int n = (t-7)*16 + lrow;
                    sfl[n & 1][row][n | 1] = acc[r];
                }
            }
        }
    }
    __syncthreads();
    if (tid < 194){
        int p = (tid >= 97) ? 1 : 0;
        int fr = tid - 97*p;
        const ushort* fb = filtb + (size_t)bc*OUTP + fr;
        float yv = sfl[p][8][fr];
        float ls = 0.f, ds = 0.f;
#pragma unroll
        for (int k=0;k<8;++k){
            float sv = sfl[p][k][fr];
            float f1 = bf2f(fb[k*FREQ]), f2 = bf2f(fb[(8+k)*FREQ]);
            ls = fmaf(sv, f1, ls);
            ds = fmaf(sv - yv, f2, ds);
        }
        float f3 = bf2f(fb[16*FREQ]);
        ushort* mrow = mixin + (size_t)bc*582 + p*291;
        mrow[fr]       = f2bf(ls);
        mrow[97 + fr]  = f2bf(ds);
        mrow[194 + fr] = f2bf(yv*f3);
    }
}

// ---------- kernel 6: MFMA y_add GEMM (13792x582)x(582x192) + denorm + store ----------
__global__ __launch_bounds__(256) void k_mix(
    const ushort* __restrict__ mixin, const ushort* __restrict__ pqfrag,
    const float* __restrict__ cst, const float* __restrict__ win,
    const float* __restrict__ w_mu, const float* __restrict__ w_std,
    float* __restrict__ out)
{
    __shared__ __align__(16) ushort Abf[16*616];
    int tid = threadIdx.x;
    int bc0 = blockIdx.x*16;
    for (int i = tid; i < 16*304; i += 256){
        int r = i/304, jc = i - r*304;
        unsigned v = 0u;
        if (jc < 291) v = *(const unsigned*)&mixin[(size_t)(bc0+r)*582 + jc*2];
        *(unsigned*)&Abf[r*616 + jc*2] = v;
    }
    __syncthreads();
    int wid = tid >> 6, lane = tid & 63;
    int lrow = lane & 15, lk8 = (lane >> 4) << 3, row0 = (lane >> 4)*4;
    f32x4 acc0 = {0.f,0.f,0.f,0.f}, acc1 = {0.f,0.f,0.f,0.f}, acc2 = {0.f,0.f,0.f,0.f};
    const ushort* pq0 = pqfrag + (size_t)((wid*3+0)*MIX_KS)*512 + lane*8;
    const ushort* pq1 = pqfrag + (size_t)((wid*3+1)*MIX_KS)*512 + lane*8;
    const ushort* pq2 = pqfrag + (size_t)((wid*3+2)*MIX_KS)*512 + lane*8;
    for (int kk = 0; kk < MIX_KS; ++kk){
        bf16x8 a = *(const bf16x8*)&Abf[lrow*616 + kk*32 + lk8];
        acc0 = __builtin_amdgcn_mfma_f32_16x16x32_bf16(a, *(const bf16x8*)(pq0 + (size_t)kk*512), acc0, 0,0,0);
        acc1 = __builtin_amdgcn_mfma_f32_16x16x32_bf16(a, *(const bf16x8*)(pq1 + (size_t)kk*512), acc1, 0,0,0);
        acc2 = __builtin_amdgcn_mfma_f32_16x16x32_bf16(a, *(const bf16x8*)(pq2 + (size_t)kk*512), acc2, 0,0,0);
    }
#pragma unroll
    for (int tl = 0; tl < 3; ++tl){
        f32x4 acc = (tl==0) ? acc0 : ((tl==1) ? acc1 : acc2);
        int h = (wid*3 + tl)*16 + lrow;
        float cs = cst[h];
#pragma unroll
        for (int r = 0; r < 4; ++r){
            int bc = bc0 + row0 + r;
            int b = bc / CC, c = bc - b*CC;
            float yn = win[(size_t)bc*WINL + 47 + h];
            float v = (acc[r] + cs + yn)*w_std[bc] + w_mu[bc];
            out[((size_t)b*HH + h)*CC + c] = v;
        }
    }
}

extern "C" void kernel_launch(void* const* d_in, const int* in_sizes, int n_in,
                              void* d_out, int out_size, void* d_ws, size_t ws_size,
                              hipStream_t stream) {
    const float* x      = (const float*)d_in[0];
    const float* y      = (const float*)d_in[1];
    const float* r_in   = (const float*)d_in[2];
    const float* temp   = (const float*)d_in[3];
    const float* cw     = (const float*)d_in[4];
    const float* bstate = (const float*)d_in[5];
    const float* sbias  = (const float*)d_in[6];
    const float* mhw    = (const float*)d_in[7];
    const float* mhb    = (const float*)d_in[8];
    const float* wr     = (const float*)d_in[9];
    const float* wi     = (const float*)d_in[10];
    const float* br     = (const float*)d_in[11];
    const float* bi     = (const float*)d_in[12];
    const int*   leader = (const int*)d_in[13];
    const int*   shiftp = (const int*)d_in[14];
    float* ws  = (float*)d_ws;
    float* out = (float*)d_out;

    size_t o_win  = 0;
    size_t o_mu   = o_win  + (size_t)NBC*WINL;
    size_t o_std  = o_mu   + NBC;
    size_t o_istd = o_std  + NBC;
    size_t o_sgn  = o_istd + NBC;
    size_t o_A    = o_sgn  + (size_t)NBC*8;
    size_t o_filt = o_A    + (size_t)NBC*80;                  // ushort buf: NBC*OUTP/2 floats
    size_t o_mix  = o_filt + (size_t)NBC*OUTP/2;              // ushort buf: NBC*582/2 floats
    size_t o_PQ   = o_mix  + (size_t)NBC*291;
    size_t o_cst  = o_PQ   + (size_t)582*HH;
    size_t o_bfr  = o_cst  + HH;                              // 19968 ushorts
    size_t o_wfr  = o_bfr  + NBFR/2;                          // 159744 ushorts
    size_t o_pqf  = o_wfr  + NWFR/2;                          // 116736 ushorts

    ushort* filtb  = (ushort*)(ws + o_filt);
    ushort* mixinb = (ushort*)(ws + o_mix);
    ushort* bfrag  = (ushort*)(ws + o_bfr);
    ushort* wfrag  = (ushort*)(ws + o_wfr);
    ushort* pqfrag = (ushort*)(ws + o_pqf);

    k_stats<<<dim3((NBC+63)/64), dim3(512), 0, stream>>>(
        x, r_in, temp, cw, bstate, sbias,
        ws+o_mu, ws+o_std, ws+o_istd, ws+o_sgn, ws+o_A);

    k_win<<<dim3(BB, 8, 27), dim3(32, 8), 0, stream>>>(
        x, y, ws+o_mu, ws+o_istd, ws+o_win);

    k_pq<<<dim3(HH), dim3(640), 0, stream>>>(
        wr, wi, br, bi, ws+o_PQ, ws+o_cst);

    k_pack<<<dim3((NBFR+NWFR+NPQF+255)/256), dim3(256), 0, stream>>>(
        mhw, mhb, ws+o_PQ, bfrag, wfrag, pqfrag);

    k_filt<<<dim3(NBC/16), dim3(256), 0, stream>>>(ws+o_A, wfrag, filtb);

    k_dft<<<dim3(NBC), dim3(256), 0, stream>>>(
        ws+o_win, filtb, ws+o_sgn, leader, shiftp, bfrag, mixinb);

    k_mix<<<dim3(NBC/16), dim3(256), 0, stream>>>(
        mixinb, pqfrag, ws+o_cst, ws+o_win, ws+o_mu, ws+o_std, out);
}